// Round 4
// baseline (4128.282 us; speedup 1.0000x reference)
//
#include <hip/hip_runtime.h>

#define NB 128
#define CL 256
#define EE 512
#define AA 128
#define LL 64
#define HH 8
#define HD 64
#define NSTEPS 20
#define BLROWS (NB*LL)   // 8192

typedef __attribute__((ext_vector_type(8))) short bf16x8;
typedef __attribute__((ext_vector_type(4))) float f32x4;
typedef unsigned int u32;

__device__ __forceinline__ unsigned short f2bf(float f) {
    union { float f; unsigned u; } x; x.f = f;
    unsigned u = x.u;
    u += 0x7fffu + ((u >> 16) & 1u);   // round-to-nearest-even
    return (unsigned short)(u >> 16);
}

// async global->LDS, 16B per lane; LDS dest = (wave-uniform base) + lane*16
__device__ __forceinline__ void async_copy16(const unsigned short* g, unsigned short* l) {
    __builtin_amdgcn_global_load_lds((const __attribute__((address_space(1))) u32*)g,
                                     (__attribute__((address_space(3))) u32*)l, 16, 0, 0);
}

// D[m][n] += sum_k A[m][k] * W[t*16+n][k] for a 16-row tile, NT n-tiles of 16.
// A/B frag layout (m89/m120 verified): lane r=lane&15 -> row, k = (lane>>4)*8 + j.
// Wbase may be LDS or global (B-fragment loads are 16B/lane coalesced).
template<int NT, int KLEN>
__device__ __forceinline__ void gemm16(const unsigned short* __restrict__ Abase, int lda,
                                       const unsigned short* __restrict__ Wbase, int ldw,
                                       f32x4* acc, int r, int q) {
#pragma unroll
    for (int kk = 0; kk < KLEN/32; ++kk) {
        bf16x8 a = *(const bf16x8*)(Abase + (size_t)r*lda + kk*32 + q*8);
#pragma unroll
        for (int t = 0; t < NT; ++t) {
            bf16x8 b = *(const bf16x8*)(Wbase + (size_t)(t*16 + r)*ldw + kk*32 + q*8);
            acc[t] = __builtin_amdgcn_mfma_f32_16x16x32_bf16(a, b, acc[t], 0, 0, 0);
        }
    }
}

// ---------------- prep kernels (run once per launch) ----------------

// vectorized fp32 -> bf16 (8 elems/thread)
__global__ void cvt8_kernel(const float* __restrict__ src, unsigned short* __restrict__ dst, int n8) {
    int i = blockIdx.x*256 + threadIdx.x;
    if (i >= n8) return;
    const float* s = src + (size_t)i*8;
    f32x4 v0 = *(const f32x4*)s;
    f32x4 v1 = *(const f32x4*)(s + 4);
    bf16x8 o;
    o[0]=(short)f2bf(v0[0]); o[1]=(short)f2bf(v0[1]);
    o[2]=(short)f2bf(v0[2]); o[3]=(short)f2bf(v0[3]);
    o[4]=(short)f2bf(v1[0]); o[5]=(short)f2bf(v1[1]);
    o[6]=(short)f2bf(v1[2]); o[7]=(short)f2bf(v1[3]);
    *(bf16x8*)(dst + (size_t)i*8) = o;
}

// Wq_eff = 0.125*(in_w[:E] @ qp_w)  (512x128);  Wo_eff = outp_w @ op_w (128x512);
// bo_eff = outp_w @ op_b + outp_b (128)
__global__ void prep_eff_kernel(const float* __restrict__ in_w, const float* __restrict__ qp_w,
                                const float* __restrict__ outp_w, const float* __restrict__ op_w,
                                const float* __restrict__ op_b, const float* __restrict__ outp_b,
                                unsigned short* __restrict__ wq, unsigned short* __restrict__ wo,
                                float* __restrict__ bo) {
    int tid = blockIdx.x*256 + threadIdx.x;
    if (tid < 65536) {
        int n = tid >> 7, k = tid & 127;
        float s = 0.f;
        for (int e = 0; e < 512; ++e) s += in_w[(size_t)n*512 + e] * qp_w[(size_t)e*128 + k];
        wq[(size_t)n*128 + k] = f2bf(s * 0.125f);
    } else if (tid < 131072) {
        int t2 = tid - 65536; int n = t2 >> 9, k = t2 & 511;
        float s = 0.f;
        for (int e = 0; e < 512; ++e) s += outp_w[(size_t)n*512 + e] * op_w[(size_t)e*512 + k];
        wo[(size_t)n*512 + k] = f2bf(s);
    } else if (tid < 131200) {
        int n = tid - 131072;
        float s = outp_b[n];
        for (int e = 0; e < 512; ++e) s += outp_w[(size_t)n*512 + e] * op_b[e];
        bo[n] = s;
    }
}

// temb[s][e] = t2_b[e] + sum_i t2_w[e,i]*relu(t_s*t1_w[i]+t1_b[i]),  t_s = 1 - 0.05 s
__global__ void temb_kernel(const float* __restrict__ t1_w, const float* __restrict__ t1_b,
                            const float* __restrict__ t2_w, const float* __restrict__ t2_b,
                            float* __restrict__ temb) {
    int tid = blockIdx.x*256 + threadIdx.x;
    if (tid >= NSTEPS*512) return;
    int s = tid >> 9, e = tid & 511;
    float t = 1.0f - 0.05f * (float)s;
    float acc = t2_b[e];
    for (int i = 0; i < 512; ++i)
        acc += t2_w[(size_t)e*512 + i] * fmaxf(t * t1_w[i] + t1_b[i], 0.f);
    temb[tid] = acc;
}

// qbias[s][n] = 0.125*(in_b[n] + sum_e in_w[n,e]*(qp_b[e]+temb[s,e]))
__global__ void qbias_kernel(const float* __restrict__ in_w, const float* __restrict__ in_b,
                             const float* __restrict__ qp_b, const float* __restrict__ temb,
                             float* __restrict__ qbias) {
    int tid = blockIdx.x*256 + threadIdx.x;
    if (tid >= NSTEPS*512) return;
    int s = tid >> 9, n = tid & 511;
    float acc = in_b[n];
    const float* te = temb + (size_t)s*512;
    for (int e = 0; e < 512; ++e)
        acc += in_w[(size_t)n*512 + e] * (qp_b[e] + te[e]);
    qbias[tid] = acc * 0.125f;
}

// ---------------- fused K+V projection GEMM ----------------
// M=32768 (b*CL+kpos), N=1024 (K cols 0..511, V cols 512..1023), K=512. bf16 A.
// XCD-aware mapping: xcd=blk&7 keeps all 8 n-tiles of an m-tile on one XCD's L2.
// BK=64, unpadded LDS staged by global_load_lds(16B) with XOR-8 group swizzle.
__global__ __launch_bounds__(512, 8) void kv_kernel(const unsigned short* __restrict__ condb,
                                                    const unsigned short* __restrict__ wkv,
                                                    const float* __restrict__ bias,
                                                    unsigned short* __restrict__ Kbuf,
                                                    unsigned short* __restrict__ Vt) {
    __shared__ unsigned short As[128*64];   // 16 KB
    __shared__ unsigned short Bs[128*64];   // 16 KB
    int tid = threadIdx.x;
    int blk = blockIdx.x;
    int xcd = blk & 7, j = blk >> 3;
    int m0 = (xcd*32 + (j >> 3)) * 128;     // 32 m-tiles per XCD
    int n0 = (j & 7) * 128;                 // n varies fastest -> A-tile reused back-to-back
    int wv = tid >> 6, lane = tid & 63, r = lane & 15, q = lane >> 4;
    int srow = lane >> 3;                   // 0..7: row within 8-row staging instr
    int sg = (lane & 7) ^ srow;             // swizzled source 16B-group
    const unsigned short* agl = condb + (size_t)(m0 + wv*16 + srow)*512 + sg*8;
    const unsigned short* bgl = wkv   + (size_t)(n0 + wv*16 + srow)*512 + sg*8;
    f32x4 acc[8] = {};
#pragma unroll
    for (int kt = 0; kt < 8; ++kt) {
        int k0 = kt * 64;
#pragma unroll
        for (int ii = 0; ii < 2; ++ii) {
            async_copy16(agl + (size_t)(ii*8)*512 + k0, &As[(wv*16 + ii*8)*64]);
            async_copy16(bgl + (size_t)(ii*8)*512 + k0, &Bs[(wv*16 + ii*8)*64]);
        }
        __syncthreads();
#pragma unroll
        for (int kk = 0; kk < 2; ++kk) {
            int gof = ((kk*4 + q) ^ (r & 7)) * 8;
            bf16x8 a = *(const bf16x8*)&As[(wv*16 + r)*64 + gof];
#pragma unroll
            for (int t = 0; t < 8; ++t) {
                bf16x8 b = *(const bf16x8*)&Bs[(t*16 + r)*64 + gof];
                acc[t] = __builtin_amdgcn_mfma_f32_16x16x32_bf16(a, b, acc[t], 0, 0, 0);
            }
        }
        __syncthreads();
    }
#pragma unroll
    for (int t = 0; t < 8; ++t) {
        int n = n0 + t*16 + r;
        float bs = bias[n];
#pragma unroll
        for (int i = 0; i < 4; ++i) {
            int m = m0 + wv*16 + q*4 + i;
            int b = m >> 8, kpos = m & 255;
            unsigned short val = f2bf(acc[t][i] + bs);
            if (n < 512) {
                int h = n >> 6, d = n & 63;
                Kbuf[((size_t)(b*HH + h)*CL + kpos)*HD + d] = val;
            } else {
                int n2 = n - 512, h = n2 >> 6, d = n2 & 63;
                Vt[((size_t)(b*HH + h)*HD + d)*CL + kpos] = val;
            }
        }
    }
}

// ---------------- persistent denoise kernel: all 20 steps, zero barriers ----
// One wave per 16-row tile (512 waves total; 2 waves/block). Each wave's 16
// rows never interact with any other wave: x lives in 32 VGPRs (fp32, D-layout)
// across all steps; D->A layout transforms go through wave-private LDS; all
// B-operands (K, Vt, weights) are MFMA fragments read directly from global
// (L1/L2/L3-served). Out-proj and FFN2 accumulate over K-dim per head / chunk.
__global__ __launch_bounds__(128) void persist_kernel(
        const unsigned short* __restrict__ Kg,   // [b*8+h][256][64]
        const unsigned short* __restrict__ Vg,   // [b*8+h][64][256]
        const float* __restrict__ noise,         // [8192][128]
        const unsigned short* __restrict__ wq,   // [512][128]  (scale folded)
        const float* __restrict__ qbiasB,        // [20][512]
        const unsigned short* __restrict__ wo,   // [128][512]
        const float* __restrict__ bo,            // [128]
        const float* __restrict__ ln_g, const float* __restrict__ ln_b,
        const unsigned short* __restrict__ f1w,  // [512][128]
        const float* __restrict__ f1_b,          // [512]
        const unsigned short* __restrict__ f2w,  // [128][512]
        const float* __restrict__ f2_b,          // [128]
        float* __restrict__ outp) {              // [8192][128] fp32
    __shared__ unsigned short xS[2][16*136];
    __shared__ unsigned short qS[2][16*72];
    __shared__ unsigned short pS[2][16*264];
    __shared__ unsigned short cS[2][16*72];
    __shared__ unsigned short hS[2][16*136];
    __shared__ unsigned short uS[2][16*136];
    int w = threadIdx.x >> 6, lane = threadIdx.x & 63, r = lane & 15, q = lane >> 4;
    int rt = blockIdx.x*2 + w;
    int row0 = rt * 16;
    int b = rt >> 2;                     // 64 rows per batch element
    unsigned short* xw = xS[w];
    unsigned short* qw = qS[w];
    unsigned short* pw = pS[w];
    unsigned short* cw = cS[w];
    unsigned short* hw = hS[w];
    unsigned short* uw = uS[w];

    // load x0 = noise into regs (D-layout: row q*4+i, col t*16+r) + LDS bf16
    float xf[8][4];
#pragma unroll
    for (int t = 0; t < 8; ++t)
#pragma unroll
        for (int i = 0; i < 4; ++i) {
            float v = noise[(size_t)(row0 + q*4 + i)*AA + t*16 + r];
            xf[t][i] = v;
            xw[(q*4 + i)*136 + t*16 + r] = f2bf(v);
        }

    const float dt = -1.f / (float)NSTEPS;
#pragma unroll 1
    for (int s = 0; s < NSTEPS; ++s) {
        const float* qb_s = qbiasB + (size_t)s*512;
        f32x4 oacc[8] = {};   // ctx @ Wo_eff^T, accumulated over heads
#pragma unroll 1
        for (int h = 0; h < 8; ++h) {
            const unsigned short* kh = Kg + (size_t)(b*HH + h)*CL*HD;
            const unsigned short* vh = Vg + (size_t)(b*HH + h)*HD*CL;
            // Q tile (16x64) = x @ Wq_eff[h]^T
            f32x4 accq[4] = {};
            gemm16<4,128>(xw, 136, wq + (size_t)h*HD*AA, AA, accq, r, q);
#pragma unroll
            for (int t = 0; t < 4; ++t) {
                float qb = qb_s[h*HD + t*16 + r];
#pragma unroll
                for (int i = 0; i < 4; ++i)
                    qw[(q*4 + i)*72 + t*16 + r] = f2bf(accq[t][i] + qb);
            }
            // S (16x256) = Q @ K_h^T  (K fragments straight from global)
            f32x4 sacc[16] = {};
            gemm16<16,64>(qw, 72, kh, HD, sacc, r, q);
            // softmax per row
#pragma unroll
            for (int i = 0; i < 4; ++i) {
                float m = sacc[0][i];
#pragma unroll
                for (int t = 1; t < 16; ++t) m = fmaxf(m, sacc[t][i]);
                m = fmaxf(m, __shfl_xor(m, 1));
                m = fmaxf(m, __shfl_xor(m, 2));
                m = fmaxf(m, __shfl_xor(m, 4));
                m = fmaxf(m, __shfl_xor(m, 8));
                float sm = 0.f;
#pragma unroll
                for (int t = 0; t < 16; ++t) { float e = __expf(sacc[t][i] - m); sacc[t][i] = e; sm += e; }
                sm += __shfl_xor(sm, 1); sm += __shfl_xor(sm, 2);
                sm += __shfl_xor(sm, 4); sm += __shfl_xor(sm, 8);
                float iv = 1.f / sm;
#pragma unroll
                for (int t = 0; t < 16; ++t)
                    pw[(q*4 + i)*264 + t*16 + r] = f2bf(sacc[t][i] * iv);
            }
            // ctx_h (16x64) = P @ V  (Vt fragments straight from global)
            f32x4 cacc[4] = {};
            gemm16<4,256>(pw, 264, vh, CL, cacc, r, q);
#pragma unroll
            for (int t = 0; t < 4; ++t)
#pragma unroll
                for (int i = 0; i < 4; ++i)
                    cw[(q*4 + i)*72 + t*16 + r] = f2bf(cacc[t][i]);
            // partial out-proj: oacc += ctx_h @ Wo_eff[:, h*64:(h+1)*64]^T
            gemm16<8,64>(cw, 72, wo + h*HD, EE, oacc, r, q);
        }

        // h = out + bo + x;  LayerNorm (row-local: quad shuffle over 16 lanes)
        float hv[8][4];
#pragma unroll
        for (int t = 0; t < 8; ++t) {
            float bov = bo[t*16 + r];
#pragma unroll
            for (int i = 0; i < 4; ++i)
                hv[t][i] = oacc[t][i] + bov + xf[t][i];
        }
        float hnv[8][4];
#pragma unroll
        for (int i = 0; i < 4; ++i) {
            float sm = 0.f, s2 = 0.f;
#pragma unroll
            for (int t = 0; t < 8; ++t) { sm += hv[t][i]; s2 += hv[t][i]*hv[t][i]; }
            sm += __shfl_xor(sm, 1); s2 += __shfl_xor(s2, 1);
            sm += __shfl_xor(sm, 2); s2 += __shfl_xor(s2, 2);
            sm += __shfl_xor(sm, 4); s2 += __shfl_xor(s2, 4);
            sm += __shfl_xor(sm, 8); s2 += __shfl_xor(s2, 8);
            float mu = sm * (1.f/128.f);
            float var = s2 * (1.f/128.f) - mu*mu;
            float rstd = rsqrtf(var + 1e-5f);
#pragma unroll
            for (int t = 0; t < 8; ++t) {
                int col = t*16 + r;
                float v = (hv[t][i] - mu) * rstd * ln_g[col] + ln_b[col];
                hnv[t][i] = v;
                hw[(q*4 + i)*136 + col] = f2bf(v);
            }
        }

        // FFN: chunked over u-cols; FFN2 accumulates per chunk
        f32x4 o2[8] = {};
#pragma unroll 1
        for (int nt = 0; nt < 4; ++nt) {
            f32x4 a1[8] = {};
            gemm16<8,128>(hw, 136, f1w + (size_t)nt*128*AA, AA, a1, r, q);
#pragma unroll
            for (int t = 0; t < 8; ++t) {
                float b1 = f1_b[nt*128 + t*16 + r];
#pragma unroll
                for (int i = 0; i < 4; ++i)
                    uw[(q*4 + i)*136 + t*16 + r] = f2bf(fmaxf(a1[t][i] + b1, 0.f));
            }
            gemm16<8,128>(uw, 136, f2w + (size_t)nt*128, EE, o2, r, q);
        }

        // x update
        if (s < NSTEPS-1) {
#pragma unroll
            for (int t = 0; t < 8; ++t) {
                float b2 = f2_b[t*16 + r];
#pragma unroll
                for (int i = 0; i < 4; ++i) {
                    float outv = hnv[t][i] + o2[t][i] + b2;
                    float xn = xf[t][i] + dt * outv;
                    xf[t][i] = xn;
                    xw[(q*4 + i)*136 + t*16 + r] = f2bf(xn);
                }
            }
        } else {
#pragma unroll
            for (int t = 0; t < 8; ++t) {
                float b2 = f2_b[t*16 + r];
#pragma unroll
                for (int i = 0; i < 4; ++i) {
                    float outv = hnv[t][i] + o2[t][i] + b2;
                    float xn = xf[t][i] + dt * outv;
                    outp[(size_t)(row0 + q*4 + i)*AA + t*16 + r] = xn;
                }
            }
        }
    }
}

extern "C" void kernel_launch(void* const* d_in, const int* in_sizes, int n_in,
                              void* d_out, int out_size, void* d_ws, size_t ws_size,
                              hipStream_t stream) {
    const float* cond   = (const float*)d_in[0];
    const float* noise  = (const float*)d_in[1];
    const float* t1_w   = (const float*)d_in[2];
    const float* t1_b   = (const float*)d_in[3];
    const float* t2_w   = (const float*)d_in[4];
    const float* t2_b   = (const float*)d_in[5];
    const float* qp_w   = (const float*)d_in[6];
    const float* qp_b   = (const float*)d_in[7];
    const float* in_w   = (const float*)d_in[8];
    const float* in_b   = (const float*)d_in[9];
    const float* op_w   = (const float*)d_in[10];
    const float* op_b   = (const float*)d_in[11];
    const float* outp_w = (const float*)d_in[12];
    const float* outp_b = (const float*)d_in[13];
    const float* f1_w   = (const float*)d_in[14];
    const float* f1_b   = (const float*)d_in[15];
    const float* f2_w   = (const float*)d_in[16];
    const float* f2_b   = (const float*)d_in[17];
    const float* ln_g   = (const float*)d_in[18];
    const float* ln_bp  = (const float*)d_in[19];

    char* w = (char*)d_ws;
    auto alloc = [&](size_t bytes) {
        char* p = w;
        w += (bytes + 255) & ~(size_t)255;
        return p;
    };
    unsigned short* Kbuf   = (unsigned short*)alloc((size_t)NB*HH*CL*HD*2);   // 33.5 MB
    unsigned short* Vt     = (unsigned short*)alloc((size_t)NB*HH*HD*CL*2);   // 33.5 MB
    unsigned short* condb  = (unsigned short*)alloc((size_t)NB*CL*EE*2);      // 33.5 MB
    unsigned short* wkv_bf = (unsigned short*)alloc((size_t)1024*512*2);      // 1 MB
    unsigned short* wq_bf  = (unsigned short*)alloc((size_t)512*128*2);
    unsigned short* wo_bf  = (unsigned short*)alloc((size_t)128*512*2);
    unsigned short* f1_bf  = (unsigned short*)alloc((size_t)512*128*2);
    unsigned short* f2_bf  = (unsigned short*)alloc((size_t)128*512*2);
    float*          bo_eff = (float*)alloc(128*4);
    float*          tembB  = (float*)alloc((size_t)NSTEPS*512*4);
    float*          qbiasB = (float*)alloc((size_t)NSTEPS*512*4);
    (void)ws_size; (void)n_in; (void)in_sizes; (void)out_size;

    // --- one-time prep ---
    cvt8_kernel<<<8192, 256, 0, stream>>>(cond, condb, NB*CL*EE/8);
    cvt8_kernel<<<256, 256, 0, stream>>>(in_w + 512*512, wkv_bf, 1024*512/8);
    cvt8_kernel<<<32, 256, 0, stream>>>(f1_w, f1_bf, 512*128/8);
    cvt8_kernel<<<32, 256, 0, stream>>>(f2_w, f2_bf, 128*512/8);
    prep_eff_kernel<<<513, 256, 0, stream>>>(in_w, qp_w, outp_w, op_w, op_b, outp_b,
                                             wq_bf, wo_bf, bo_eff);
    temb_kernel<<<40, 256, 0, stream>>>(t1_w, t1_b, t2_w, t2_b, tembB);
    qbias_kernel<<<40, 256, 0, stream>>>(in_w, in_b, qp_b, tembB, qbiasB);
    kv_kernel<<<2048, 512, 0, stream>>>(condb, wkv_bf, in_b + 512, Kbuf, Vt);

    // --- all 20 denoise steps in ONE kernel (512 independent waves) ---
    persist_kernel<<<256, 128, 0, stream>>>(Kbuf, Vt, noise, wq_bf, qbiasB,
                                            wo_bf, bo_eff, ln_g, ln_bp,
                                            f1_bf, f1_b, f2_bf, f2_b,
                                            (float*)d_out);
}

// Round 5
// 1914.148 us; speedup vs baseline: 2.1567x; 2.1567x over previous
//
#include <hip/hip_runtime.h>

#define NB 128
#define CL 256
#define EE 512
#define AA 128
#define LL 64
#define HH 8
#define HD 64
#define NSTEPS 20
#define BLROWS (NB*LL)   // 8192

typedef __attribute__((ext_vector_type(8))) short bf16x8;
typedef __attribute__((ext_vector_type(4))) float f32x4;
typedef unsigned int u32;

union U8 { u32 u[4]; bf16x8 v; };

__device__ __forceinline__ unsigned short f2bf(float f) {
    union { float f; unsigned u; } x; x.f = f;
    unsigned u = x.u;
    u += 0x7fffu + ((u >> 16) & 1u);   // round-to-nearest-even
    return (unsigned short)(u >> 16);
}
__device__ __forceinline__ u32 pk(float a, float b) {
    return (u32)f2bf(a) | ((u32)f2bf(b) << 16);
}

// async global->LDS, 16B per lane
__device__ __forceinline__ void async_copy16(const unsigned short* g, unsigned short* l) {
    __builtin_amdgcn_global_load_lds((const __attribute__((address_space(1))) u32*)g,
                                     (__attribute__((address_space(3))) u32*)l, 16, 0, 0);
}

#define MFMA(a,b,c) __builtin_amdgcn_mfma_f32_16x16x32_bf16(a, b, c, 0, 0, 0)

// ---------------- prep kernels (unchanged from round 3) ----------------

__global__ void cvt8_kernel(const float* __restrict__ src, unsigned short* __restrict__ dst, int n8) {
    int i = blockIdx.x*256 + threadIdx.x;
    if (i >= n8) return;
    const float* s = src + (size_t)i*8;
    f32x4 v0 = *(const f32x4*)s;
    f32x4 v1 = *(const f32x4*)(s + 4);
    bf16x8 o;
    o[0]=(short)f2bf(v0[0]); o[1]=(short)f2bf(v0[1]);
    o[2]=(short)f2bf(v0[2]); o[3]=(short)f2bf(v0[3]);
    o[4]=(short)f2bf(v1[0]); o[5]=(short)f2bf(v1[1]);
    o[6]=(short)f2bf(v1[2]); o[7]=(short)f2bf(v1[3]);
    *(bf16x8*)(dst + (size_t)i*8) = o;
}

__global__ void prep_eff_kernel(const float* __restrict__ in_w, const float* __restrict__ qp_w,
                                const float* __restrict__ outp_w, const float* __restrict__ op_w,
                                const float* __restrict__ op_b, const float* __restrict__ outp_b,
                                unsigned short* __restrict__ wq, unsigned short* __restrict__ wo,
                                float* __restrict__ bo) {
    int tid = blockIdx.x*256 + threadIdx.x;
    if (tid < 65536) {
        int n = tid >> 7, k = tid & 127;
        float s = 0.f;
        for (int e = 0; e < 512; ++e) s += in_w[(size_t)n*512 + e] * qp_w[(size_t)e*128 + k];
        wq[(size_t)n*128 + k] = f2bf(s * 0.125f);
    } else if (tid < 131072) {
        int t2 = tid - 65536; int n = t2 >> 9, k = t2 & 511;
        float s = 0.f;
        for (int e = 0; e < 512; ++e) s += outp_w[(size_t)n*512 + e] * op_w[(size_t)e*512 + k];
        wo[(size_t)n*512 + k] = f2bf(s);
    } else if (tid < 131200) {
        int n = tid - 131072;
        float s = outp_b[n];
        for (int e = 0; e < 512; ++e) s += outp_w[(size_t)n*512 + e] * op_b[e];
        bo[n] = s;
    }
}

__global__ void temb_kernel(const float* __restrict__ t1_w, const float* __restrict__ t1_b,
                            const float* __restrict__ t2_w, const float* __restrict__ t2_b,
                            float* __restrict__ temb) {
    int tid = blockIdx.x*256 + threadIdx.x;
    if (tid >= NSTEPS*512) return;
    int s = tid >> 9, e = tid & 511;
    float t = 1.0f - 0.05f * (float)s;
    float acc = t2_b[e];
    for (int i = 0; i < 512; ++i)
        acc += t2_w[(size_t)e*512 + i] * fmaxf(t * t1_w[i] + t1_b[i], 0.f);
    temb[tid] = acc;
}

__global__ void qbias_kernel(const float* __restrict__ in_w, const float* __restrict__ in_b,
                             const float* __restrict__ qp_b, const float* __restrict__ temb,
                             float* __restrict__ qbias) {
    int tid = blockIdx.x*256 + threadIdx.x;
    if (tid >= NSTEPS*512) return;
    int s = tid >> 9, n = tid & 511;
    float acc = in_b[n];
    const float* te = temb + (size_t)s*512;
    for (int e = 0; e < 512; ++e)
        acc += in_w[(size_t)n*512 + e] * (qp_b[e] + te[e]);
    qbias[tid] = acc * 0.125f;
}

// ---------------- fused K+V projection GEMM (unchanged from round 3) ----
__global__ __launch_bounds__(512, 8) void kv_kernel(const unsigned short* __restrict__ condb,
                                                    const unsigned short* __restrict__ wkv,
                                                    const float* __restrict__ bias,
                                                    unsigned short* __restrict__ Kbuf,
                                                    unsigned short* __restrict__ Vt) {
    __shared__ unsigned short As[128*64];
    __shared__ unsigned short Bs[128*64];
    int tid = threadIdx.x;
    int blk = blockIdx.x;
    int xcd = blk & 7, j = blk >> 3;
    int m0 = (xcd*32 + (j >> 3)) * 128;
    int n0 = (j & 7) * 128;
    int wv = tid >> 6, lane = tid & 63, r = lane & 15, q = lane >> 4;
    int srow = lane >> 3;
    int sg = (lane & 7) ^ srow;
    const unsigned short* agl = condb + (size_t)(m0 + wv*16 + srow)*512 + sg*8;
    const unsigned short* bgl = wkv   + (size_t)(n0 + wv*16 + srow)*512 + sg*8;
    f32x4 acc[8] = {};
#pragma unroll
    for (int kt = 0; kt < 8; ++kt) {
        int k0 = kt * 64;
#pragma unroll
        for (int ii = 0; ii < 2; ++ii) {
            async_copy16(agl + (size_t)(ii*8)*512 + k0, &As[(wv*16 + ii*8)*64]);
            async_copy16(bgl + (size_t)(ii*8)*512 + k0, &Bs[(wv*16 + ii*8)*64]);
        }
        __syncthreads();
#pragma unroll
        for (int kk = 0; kk < 2; ++kk) {
            int gof = ((kk*4 + q) ^ (r & 7)) * 8;
            bf16x8 a = *(const bf16x8*)&As[(wv*16 + r)*64 + gof];
#pragma unroll
            for (int t = 0; t < 8; ++t) {
                bf16x8 b = *(const bf16x8*)&Bs[(t*16 + r)*64 + gof];
                acc[t] = MFMA(a, b, acc[t]);
            }
        }
        __syncthreads();
    }
#pragma unroll
    for (int t = 0; t < 8; ++t) {
        int n = n0 + t*16 + r;
        float bs = bias[n];
#pragma unroll
        for (int i = 0; i < 4; ++i) {
            int m = m0 + wv*16 + q*4 + i;
            int b = m >> 8, kpos = m & 255;
            unsigned short val = f2bf(acc[t][i] + bs);
            if (n < 512) {
                int h = n >> 6, d = n & 63;
                Kbuf[((size_t)(b*HH + h)*CL + kpos)*HD + d] = val;
            } else {
                int n2 = n - 512, h = n2 >> 6, d = n2 & 63;
                Vt[((size_t)(b*HH + h)*HD + d)*CL + kpos] = val;
            }
        }
    }
}

// ---------------- mega kernel: all 20 steps, 8-wave blocks of 32 rows ------
// Block = 32 rows of batch b (2 blocks per b, same-XCD via swizzle). Phase A:
// wave w -> q-tile (w&1), heads {w>>1, (w>>1)+4}: Q^T-proj (A=wq global,
// B=x LDS), S^T (A=K global, B=Q via shfl-transpose), softmax per-lane rows,
// PV (A=P via shfl-transpose, B=Vt global) -> ctx LDS. Phase B: wave w ->
// tile (w&1), cols (w>>1)*32: out-proj + residual + LN (cross-wave LDS
// reduce), chunked FFN with double-buffered uS, x update (fp32 in regs).
__global__ __launch_bounds__(512, 4) void mega_kernel(
        const unsigned short* __restrict__ Kg,   // [b*8+h][256][64]
        const unsigned short* __restrict__ Vg,   // [b*8+h][64][256]
        const float* __restrict__ noise,
        const unsigned short* __restrict__ wq,   // [512][128]
        const float* __restrict__ qbiasB,        // [20][512]
        const unsigned short* __restrict__ wo,   // [128][512]
        const float* __restrict__ bo,
        const float* __restrict__ ln_g, const float* __restrict__ ln_b,
        const unsigned short* __restrict__ f1w,  // [512][128]
        const float* __restrict__ f1_b,
        const unsigned short* __restrict__ f2w,  // [128][512]
        const float* __restrict__ f2_b,
        float* __restrict__ outp) {
    __shared__ unsigned short xS[32*136];     // 8.7 KB
    __shared__ unsigned short ctxS[32*520];   // 33.3 KB
    __shared__ unsigned short hnS[32*136];    // 8.7 KB
    __shared__ unsigned short uS[2][32*136];  // 17.4 KB
    __shared__ float redS[32*4], redS2[32*4];

    int tid = threadIdx.x, w = tid >> 6, lane = tid & 63, r = lane & 15, q = lane >> 4;
    int vblk = ((blockIdx.x & 7) << 5) | (blockIdx.x >> 3);   // pairs (2b,2b+1) same XCD
    int b = vblk >> 1;
    int row0 = vblk * 32;
    int tA = w & 1, gA = w >> 1;          // phase A: tile, head-group
    int tB = w & 1, cg = w >> 1;          // phase B: tile, col-group (cols cg*32)
    int srcA = r + ((2*q) & 3)*16;
    int srcB = r + ((2*q + 1) & 3)*16;
    int odd = (q >> 1) & 1;

    // init x from noise (each phase-B wave owns rows tB*16.., cols cg*32..)
    float xf[2][4];
#pragma unroll
    for (int t = 0; t < 2; ++t)
#pragma unroll
        for (int i = 0; i < 4; ++i) {
            int rl = tB*16 + q*4 + i, col = cg*32 + t*16 + r;
            float v = noise[(size_t)(row0 + rl)*AA + col];
            xf[t][i] = v;
            xS[rl*136 + col] = f2bf(v);
        }
    __syncthreads();

    const float dt = -1.f / (float)NSTEPS;
#pragma unroll 1
    for (int s = 0; s < NSTEPS; ++s) {
        const float* qb_s = qbiasB + (size_t)s*512;
        // ================= Phase A: attention -> ctxS =================
#pragma unroll 1
        for (int hh = 0; hh < 2; ++hh) {
            int h = gA + hh*4;
            size_t bh = (size_t)b*HH + h;
            // Q^T-proj: D[d-tile][x-row]; A = wq rows (global), B = x rows (LDS)
            f32x4 qacc[4] = {};
#pragma unroll
            for (int kk = 0; kk < 4; ++kk) {
                bf16x8 bx = *(const bf16x8*)&xS[(tA*16 + r)*136 + kk*32 + q*8];
#pragma unroll
                for (int t = 0; t < 4; ++t) {
                    bf16x8 a = *(const bf16x8*)(wq + (size_t)(h*HD + t*16 + r)*AA + kk*32 + q*8);
                    qacc[t] = MFMA(a, bx, qacc[t]);
                }
            }
            u32 qp[4][2];
#pragma unroll
            for (int t = 0; t < 4; ++t) {
                f32x4 qb4 = *(const f32x4*)(qb_s + h*HD + t*16 + q*4);
                qp[t][0] = pk(qacc[t][0] + qb4[0], qacc[t][1] + qb4[1]);
                qp[t][1] = pk(qacc[t][2] + qb4[2], qacc[t][3] + qb4[3]);
            }
            // Q as B-operand via shfl-transpose (lane&15 axis shared)
            U8 bq[2];
#pragma unroll
            for (int kd = 0; kd < 2; ++kd) {
                u32 e0 = __shfl((int)qp[kd*2][0], srcA, 64), o0 = __shfl((int)qp[kd*2+1][0], srcA, 64);
                u32 e1 = __shfl((int)qp[kd*2][1], srcA, 64), o1 = __shfl((int)qp[kd*2+1][1], srcA, 64);
                u32 e2 = __shfl((int)qp[kd*2][0], srcB, 64), o2 = __shfl((int)qp[kd*2+1][0], srcB, 64);
                u32 e3 = __shfl((int)qp[kd*2][1], srcB, 64), o3 = __shfl((int)qp[kd*2+1][1], srcB, 64);
                bq[kd].u[0] = odd ? o0 : e0;  bq[kd].u[1] = odd ? o1 : e1;
                bq[kd].u[2] = odd ? o2 : e2;  bq[kd].u[3] = odd ? o3 : e3;
            }
            // S^T: A = K rows (global), B = Q. Lane holds S[q-row r][64 k-pos]
            f32x4 sacc[16] = {};
            const unsigned short* kbase = Kg + bh*CL*HD;
#pragma unroll
            for (int t = 0; t < 16; ++t)
#pragma unroll
                for (int kd = 0; kd < 2; ++kd) {
                    bf16x8 a = *(const bf16x8*)(kbase + (size_t)(t*16 + r)*HD + kd*32 + q*8);
                    sacc[t] = MFMA(a, bq[kd].v, sacc[t]);
                }
            // softmax over row r (64 regs + cross-quad shuffles)
            float mx = sacc[0][0];
#pragma unroll
            for (int t = 0; t < 16; ++t)
#pragma unroll
                for (int i = 0; i < 4; ++i) mx = fmaxf(mx, sacc[t][i]);
            mx = fmaxf(mx, __shfl_xor(mx, 16));
            mx = fmaxf(mx, __shfl_xor(mx, 32));
            float sum = 0.f;
#pragma unroll
            for (int t = 0; t < 16; ++t)
#pragma unroll
                for (int i = 0; i < 4; ++i) {
                    float e = __expf(sacc[t][i] - mx); sacc[t][i] = e; sum += e;
                }
            sum += __shfl_xor(sum, 16);
            sum += __shfl_xor(sum, 32);
            float iv = 1.f / sum;
            u32 pp[16][2];
#pragma unroll
            for (int t = 0; t < 16; ++t) {
                pp[t][0] = pk(sacc[t][0]*iv, sacc[t][1]*iv);
                pp[t][1] = pk(sacc[t][2]*iv, sacc[t][3]*iv);
            }
            // PV: A = P via shfl-transpose, B = Vt rows (global)
            f32x4 cacc[4] = {};
            const unsigned short* vbase = Vg + bh*HD*CL;
#pragma unroll
            for (int kk = 0; kk < 8; ++kk) {
                U8 ap;
                u32 e0 = __shfl((int)pp[kk*2][0], srcA, 64), o0 = __shfl((int)pp[kk*2+1][0], srcA, 64);
                u32 e1 = __shfl((int)pp[kk*2][1], srcA, 64), o1 = __shfl((int)pp[kk*2+1][1], srcA, 64);
                u32 e2 = __shfl((int)pp[kk*2][0], srcB, 64), o2 = __shfl((int)pp[kk*2+1][0], srcB, 64);
                u32 e3 = __shfl((int)pp[kk*2][1], srcB, 64), o3 = __shfl((int)pp[kk*2+1][1], srcB, 64);
                ap.u[0] = odd ? o0 : e0;  ap.u[1] = odd ? o1 : e1;
                ap.u[2] = odd ? o2 : e2;  ap.u[3] = odd ? o3 : e3;
#pragma unroll
                for (int t = 0; t < 4; ++t) {
                    bf16x8 bv = *(const bf16x8*)(vbase + (size_t)(t*16 + r)*CL + kk*32 + q*8);
                    cacc[t] = MFMA(ap.v, bv, cacc[t]);
                }
            }
            // ctx_h -> LDS (D-layout scatter)
#pragma unroll
            for (int t = 0; t < 4; ++t)
#pragma unroll
                for (int i = 0; i < 4; ++i)
                    ctxS[(tA*16 + q*4 + i)*520 + h*HD + t*16 + r] = f2bf(cacc[t][i]);
        }
        __syncthreads();   // ctx complete

        // ============ Phase B: out-proj + residual + LayerNorm ============
        f32x4 oacc[2] = {};
#pragma unroll
        for (int kk = 0; kk < 16; ++kk) {
            bf16x8 a = *(const bf16x8*)&ctxS[(tB*16 + r)*520 + kk*32 + q*8];
#pragma unroll
            for (int t = 0; t < 2; ++t) {
                bf16x8 bw = *(const bf16x8*)(wo + (size_t)(cg*32 + t*16 + r)*EE + kk*32 + q*8);
                oacc[t] = MFMA(a, bw, oacc[t]);
            }
        }
        float hv[2][4];
#pragma unroll
        for (int t = 0; t < 2; ++t) {
            float bov = bo[cg*32 + t*16 + r];
#pragma unroll
            for (int i = 0; i < 4; ++i) hv[t][i] = oacc[t][i] + bov + xf[t][i];
        }
#pragma unroll
        for (int i = 0; i < 4; ++i) {
            float s1 = hv[0][i] + hv[1][i];
            float s2 = hv[0][i]*hv[0][i] + hv[1][i]*hv[1][i];
            s1 += __shfl_xor(s1, 1);  s2 += __shfl_xor(s2, 1);
            s1 += __shfl_xor(s1, 2);  s2 += __shfl_xor(s2, 2);
            s1 += __shfl_xor(s1, 4);  s2 += __shfl_xor(s2, 4);
            s1 += __shfl_xor(s1, 8);  s2 += __shfl_xor(s2, 8);
            if (r == 0) { redS[(tB*16 + q*4 + i)*4 + cg] = s1; redS2[(tB*16 + q*4 + i)*4 + cg] = s2; }
        }
        __syncthreads();
        float hnv[2][4];
#pragma unroll
        for (int i = 0; i < 4; ++i) {
            int row = tB*16 + q*4 + i;
            float s1 = redS [row*4+0] + redS [row*4+1] + redS [row*4+2] + redS [row*4+3];
            float s2 = redS2[row*4+0] + redS2[row*4+1] + redS2[row*4+2] + redS2[row*4+3];
            float mu = s1 * (1.f/128.f);
            float var = s2 * (1.f/128.f) - mu*mu;
            float rstd = rsqrtf(var + 1e-5f);
#pragma unroll
            for (int t = 0; t < 2; ++t) {
                int col = cg*32 + t*16 + r;
                float v = (hv[t][i] - mu) * rstd * ln_g[col] + ln_b[col];
                hnv[t][i] = v;
                hnS[row*136 + col] = f2bf(v);
            }
        }
        __syncthreads();

        // ================= FFN (chunked, double-buffered uS) ==============
        f32x4 o2[2] = {};
#pragma unroll 1
        for (int nt = 0; nt < 4; ++nt) {
            f32x4 a1[2] = {};
#pragma unroll
            for (int kk = 0; kk < 4; ++kk) {
                bf16x8 a = *(const bf16x8*)&hnS[(tB*16 + r)*136 + kk*32 + q*8];
#pragma unroll
                for (int t = 0; t < 2; ++t) {
                    bf16x8 bw = *(const bf16x8*)(f1w + (size_t)(nt*128 + cg*32 + t*16 + r)*AA + kk*32 + q*8);
                    a1[t] = MFMA(a, bw, a1[t]);
                }
            }
            unsigned short* up = uS[nt & 1];
#pragma unroll
            for (int t = 0; t < 2; ++t) {
                float b1 = f1_b[nt*128 + cg*32 + t*16 + r];
#pragma unroll
                for (int i = 0; i < 4; ++i)
                    up[(tB*16 + q*4 + i)*136 + cg*32 + t*16 + r] = f2bf(fmaxf(a1[t][i] + b1, 0.f));
            }
            __syncthreads();
#pragma unroll
            for (int kk = 0; kk < 4; ++kk) {
                bf16x8 a = *(const bf16x8*)&up[(tB*16 + r)*136 + kk*32 + q*8];
#pragma unroll
                for (int t = 0; t < 2; ++t) {
                    bf16x8 bw = *(const bf16x8*)(f2w + (size_t)(cg*32 + t*16 + r)*EE + nt*128 + kk*32 + q*8);
                    o2[t] = MFMA(a, bw, o2[t]);
                }
            }
        }

        // ===================== x update =====================
        if (s < NSTEPS - 1) {
#pragma unroll
            for (int t = 0; t < 2; ++t) {
                float b2 = f2_b[cg*32 + t*16 + r];
#pragma unroll
                for (int i = 0; i < 4; ++i) {
                    float outv = hnv[t][i] + o2[t][i] + b2;
                    float xn = xf[t][i] + dt * outv;
                    xf[t][i] = xn;
                    xS[(tB*16 + q*4 + i)*136 + cg*32 + t*16 + r] = f2bf(xn);
                }
            }
            __syncthreads();   // xS ready for next step's phase A
        } else {
#pragma unroll
            for (int t = 0; t < 2; ++t) {
                float b2 = f2_b[cg*32 + t*16 + r];
#pragma unroll
                for (int i = 0; i < 4; ++i) {
                    float outv = hnv[t][i] + o2[t][i] + b2;
                    outp[(size_t)(row0 + tB*16 + q*4 + i)*AA + cg*32 + t*16 + r] = xf[t][i] + dt * outv;
                }
            }
        }
    }
}

extern "C" void kernel_launch(void* const* d_in, const int* in_sizes, int n_in,
                              void* d_out, int out_size, void* d_ws, size_t ws_size,
                              hipStream_t stream) {
    const float* cond   = (const float*)d_in[0];
    const float* noise  = (const float*)d_in[1];
    const float* t1_w   = (const float*)d_in[2];
    const float* t1_b   = (const float*)d_in[3];
    const float* t2_w   = (const float*)d_in[4];
    const float* t2_b   = (const float*)d_in[5];
    const float* qp_w   = (const float*)d_in[6];
    const float* qp_b   = (const float*)d_in[7];
    const float* in_w   = (const float*)d_in[8];
    const float* in_b   = (const float*)d_in[9];
    const float* op_w   = (const float*)d_in[10];
    const float* op_b   = (const float*)d_in[11];
    const float* outp_w = (const float*)d_in[12];
    const float* outp_b = (const float*)d_in[13];
    const float* f1_w   = (const float*)d_in[14];
    const float* f1_b   = (const float*)d_in[15];
    const float* f2_w   = (const float*)d_in[16];
    const float* f2_b   = (const float*)d_in[17];
    const float* ln_g   = (const float*)d_in[18];
    const float* ln_bp  = (const float*)d_in[19];

    char* w = (char*)d_ws;
    auto alloc = [&](size_t bytes) {
        char* p = w;
        w += (bytes + 255) & ~(size_t)255;
        return p;
    };
    unsigned short* Kbuf   = (unsigned short*)alloc((size_t)NB*HH*CL*HD*2);   // 33.5 MB
    unsigned short* Vt     = (unsigned short*)alloc((size_t)NB*HH*HD*CL*2);   // 33.5 MB
    unsigned short* condb  = (unsigned short*)alloc((size_t)NB*CL*EE*2);      // 33.5 MB
    unsigned short* wkv_bf = (unsigned short*)alloc((size_t)1024*512*2);      // 1 MB
    unsigned short* wq_bf  = (unsigned short*)alloc((size_t)512*128*2);
    unsigned short* wo_bf  = (unsigned short*)alloc((size_t)128*512*2);
    unsigned short* f1_bf  = (unsigned short*)alloc((size_t)512*128*2);
    unsigned short* f2_bf  = (unsigned short*)alloc((size_t)128*512*2);
    float*          bo_eff = (float*)alloc(128*4);
    float*          tembB  = (float*)alloc((size_t)NSTEPS*512*4);
    float*          qbiasB = (float*)alloc((size_t)NSTEPS*512*4);
    (void)ws_size; (void)n_in; (void)in_sizes; (void)out_size;

    // --- one-time prep ---
    cvt8_kernel<<<8192, 256, 0, stream>>>(cond, condb, NB*CL*EE/8);
    cvt8_kernel<<<256, 256, 0, stream>>>(in_w + 512*512, wkv_bf, 1024*512/8);
    cvt8_kernel<<<32, 256, 0, stream>>>(f1_w, f1_bf, 512*128/8);
    cvt8_kernel<<<32, 256, 0, stream>>>(f2_w, f2_bf, 128*512/8);
    prep_eff_kernel<<<513, 256, 0, stream>>>(in_w, qp_w, outp_w, op_w, op_b, outp_b,
                                             wq_bf, wo_bf, bo_eff);
    temb_kernel<<<40, 256, 0, stream>>>(t1_w, t1_b, t2_w, t2_b, tembB);
    qbias_kernel<<<40, 256, 0, stream>>>(in_w, in_b, qp_b, tembB, qbiasB);
    kv_kernel<<<2048, 512, 0, stream>>>(condb, wkv_bf, in_b + 512, Kbuf, Vt);

    // --- all 20 denoise steps, one kernel, 256 blocks x 8 waves ---
    mega_kernel<<<256, 512, 0, stream>>>(Kbuf, Vt, noise, wq_bf, qbiasB,
                                         wo_bf, bo_eff, ln_g, ln_bp,
                                         f1_bf, f1_b, f2_bf, f2_b,
                                         (float*)d_out);
}

// Round 6
// 1868.482 us; speedup vs baseline: 2.2094x; 1.0244x over previous
//
#include <hip/hip_runtime.h>

#define NB 128
#define CL 256
#define EE 512
#define AA 128
#define LL 64
#define HH 8
#define HD 64
#define NSTEPS 20
#define BLROWS (NB*LL)   // 8192
#define LOG2E 1.4426950408889634f

typedef __attribute__((ext_vector_type(8))) short bf16x8;
typedef __attribute__((ext_vector_type(4))) float f32x4;
typedef unsigned int u32;

union U8 { u32 u[4]; bf16x8 v; };

__device__ __forceinline__ unsigned short f2bf(float f) {
    union { float f; unsigned u; } x; x.f = f;
    unsigned u = x.u;
    u += 0x7fffu + ((u >> 16) & 1u);   // round-to-nearest-even
    return (unsigned short)(u >> 16);
}
__device__ __forceinline__ u32 pk(float a, float b) {
    return (u32)f2bf(a) | ((u32)f2bf(b) << 16);
}

// async global->LDS, 16B per lane
__device__ __forceinline__ void async_copy16(const unsigned short* g, unsigned short* l) {
    __builtin_amdgcn_global_load_lds((const __attribute__((address_space(1))) u32*)g,
                                     (__attribute__((address_space(3))) u32*)l, 16, 0, 0);
}

#define MFMA(a,b,c) __builtin_amdgcn_mfma_f32_16x16x32_bf16(a, b, c, 0, 0, 0)

// D-layout (col=lane&15 pairs) -> A/B-operand layout (row=lane&15, k=quad*8+j)
// via cross-quad shuffles; verified in round-4/5 mega (passed).
__device__ __forceinline__ U8 build_ap(const u32 (*pp)[2], int kk,
                                       int srcA, int srcB, int odd) {
    U8 ap;
    u32 e0 = __shfl((int)pp[kk*2][0], srcA, 64), o0 = __shfl((int)pp[kk*2+1][0], srcA, 64);
    u32 e1 = __shfl((int)pp[kk*2][1], srcA, 64), o1 = __shfl((int)pp[kk*2+1][1], srcA, 64);
    u32 e2 = __shfl((int)pp[kk*2][0], srcB, 64), o2 = __shfl((int)pp[kk*2+1][0], srcB, 64);
    u32 e3 = __shfl((int)pp[kk*2][1], srcB, 64), o3 = __shfl((int)pp[kk*2+1][1], srcB, 64);
    ap.u[0] = odd ? o0 : e0;  ap.u[1] = odd ? o1 : e1;
    ap.u[2] = odd ? o2 : e2;  ap.u[3] = odd ? o3 : e3;
    return ap;
}

// softmax over 256 scores held as sacc[16] (per-lane 64 + cross-quad xor),
// base-2 domain (log2e folded into Q); packs normalized P into pp.
__device__ __forceinline__ void softmax_pack(f32x4* sacc, u32 (*pp)[2]) {
    float mx = sacc[0][0];
#pragma unroll
    for (int t = 0; t < 16; ++t)
#pragma unroll
        for (int i = 0; i < 4; ++i) mx = fmaxf(mx, sacc[t][i]);
    mx = fmaxf(mx, __shfl_xor(mx, 16));
    mx = fmaxf(mx, __shfl_xor(mx, 32));
    float sum = 0.f;
#pragma unroll
    for (int t = 0; t < 16; ++t)
#pragma unroll
        for (int i = 0; i < 4; ++i) {
            float e = exp2f(sacc[t][i] - mx); sacc[t][i] = e; sum += e;
        }
    sum += __shfl_xor(sum, 16);
    sum += __shfl_xor(sum, 32);
    float iv = 1.f / sum;
#pragma unroll
    for (int t = 0; t < 16; ++t) {
        pp[t][0] = pk(sacc[t][0]*iv, sacc[t][1]*iv);
        pp[t][1] = pk(sacc[t][2]*iv, sacc[t][3]*iv);
    }
}

// ---------------- prep kernels ----------------

__global__ void cvt8_kernel(const float* __restrict__ src, unsigned short* __restrict__ dst, int n8) {
    int i = blockIdx.x*256 + threadIdx.x;
    if (i >= n8) return;
    const float* s = src + (size_t)i*8;
    f32x4 v0 = *(const f32x4*)s;
    f32x4 v1 = *(const f32x4*)(s + 4);
    bf16x8 o;
    o[0]=(short)f2bf(v0[0]); o[1]=(short)f2bf(v0[1]);
    o[2]=(short)f2bf(v0[2]); o[3]=(short)f2bf(v0[3]);
    o[4]=(short)f2bf(v1[0]); o[5]=(short)f2bf(v1[1]);
    o[6]=(short)f2bf(v1[2]); o[7]=(short)f2bf(v1[3]);
    *(bf16x8*)(dst + (size_t)i*8) = o;
}

// Wq_eff = (0.125*log2e)*(in_w[:E] @ qp_w); Wo_eff = outp_w @ op_w; bo_eff
__global__ void prep_eff_kernel(const float* __restrict__ in_w, const float* __restrict__ qp_w,
                                const float* __restrict__ outp_w, const float* __restrict__ op_w,
                                const float* __restrict__ op_b, const float* __restrict__ outp_b,
                                unsigned short* __restrict__ wq, unsigned short* __restrict__ wo,
                                float* __restrict__ bo) {
    int tid = blockIdx.x*256 + threadIdx.x;
    if (tid < 65536) {
        int n = tid >> 7, k = tid & 127;
        float s = 0.f;
        for (int e = 0; e < 512; ++e) s += in_w[(size_t)n*512 + e] * qp_w[(size_t)e*128 + k];
        wq[(size_t)n*128 + k] = f2bf(s * (0.125f * LOG2E));
    } else if (tid < 131072) {
        int t2 = tid - 65536; int n = t2 >> 9, k = t2 & 511;
        float s = 0.f;
        for (int e = 0; e < 512; ++e) s += outp_w[(size_t)n*512 + e] * op_w[(size_t)e*512 + k];
        wo[(size_t)n*512 + k] = f2bf(s);
    } else if (tid < 131200) {
        int n = tid - 131072;
        float s = outp_b[n];
        for (int e = 0; e < 512; ++e) s += outp_w[(size_t)n*512 + e] * op_b[e];
        bo[n] = s;
    }
}

__global__ void temb_kernel(const float* __restrict__ t1_w, const float* __restrict__ t1_b,
                            const float* __restrict__ t2_w, const float* __restrict__ t2_b,
                            float* __restrict__ temb) {
    int tid = blockIdx.x*256 + threadIdx.x;
    if (tid >= NSTEPS*512) return;
    int s = tid >> 9, e = tid & 511;
    float t = 1.0f - 0.05f * (float)s;
    float acc = t2_b[e];
    for (int i = 0; i < 512; ++i)
        acc += t2_w[(size_t)e*512 + i] * fmaxf(t * t1_w[i] + t1_b[i], 0.f);
    temb[tid] = acc;
}

__global__ void qbias_kernel(const float* __restrict__ in_w, const float* __restrict__ in_b,
                             const float* __restrict__ qp_b, const float* __restrict__ temb,
                             float* __restrict__ qbias) {
    int tid = blockIdx.x*256 + threadIdx.x;
    if (tid >= NSTEPS*512) return;
    int s = tid >> 9, n = tid & 511;
    float acc = in_b[n];
    const float* te = temb + (size_t)s*512;
    for (int e = 0; e < 512; ++e)
        acc += in_w[(size_t)n*512 + e] * (qp_b[e] + te[e]);
    qbias[tid] = acc * (0.125f * LOG2E);
}

// ---------------- fused K+V projection GEMM (unchanged) ----------------
__global__ __launch_bounds__(512, 8) void kv_kernel(const unsigned short* __restrict__ condb,
                                                    const unsigned short* __restrict__ wkv,
                                                    const float* __restrict__ bias,
                                                    unsigned short* __restrict__ Kbuf,
                                                    unsigned short* __restrict__ Vt) {
    __shared__ unsigned short As[128*64];
    __shared__ unsigned short Bs[128*64];
    int tid = threadIdx.x;
    int blk = blockIdx.x;
    int xcd = blk & 7, j = blk >> 3;
    int m0 = (xcd*32 + (j >> 3)) * 128;
    int n0 = (j & 7) * 128;
    int wv = tid >> 6, lane = tid & 63, r = lane & 15, q = lane >> 4;
    int srow = lane >> 3;
    int sg = (lane & 7) ^ srow;
    const unsigned short* agl = condb + (size_t)(m0 + wv*16 + srow)*512 + sg*8;
    const unsigned short* bgl = wkv   + (size_t)(n0 + wv*16 + srow)*512 + sg*8;
    f32x4 acc[8] = {};
#pragma unroll
    for (int kt = 0; kt < 8; ++kt) {
        int k0 = kt * 64;
#pragma unroll
        for (int ii = 0; ii < 2; ++ii) {
            async_copy16(agl + (size_t)(ii*8)*512 + k0, &As[(wv*16 + ii*8)*64]);
            async_copy16(bgl + (size_t)(ii*8)*512 + k0, &Bs[(wv*16 + ii*8)*64]);
        }
        __syncthreads();
#pragma unroll
        for (int kk = 0; kk < 2; ++kk) {
            int gof = ((kk*4 + q) ^ (r & 7)) * 8;
            bf16x8 a = *(const bf16x8*)&As[(wv*16 + r)*64 + gof];
#pragma unroll
            for (int t = 0; t < 8; ++t) {
                bf16x8 b = *(const bf16x8*)&Bs[(t*16 + r)*64 + gof];
                acc[t] = MFMA(a, b, acc[t]);
            }
        }
        __syncthreads();
    }
#pragma unroll
    for (int t = 0; t < 8; ++t) {
        int n = n0 + t*16 + r;
        float bs = bias[n];
#pragma unroll
        for (int i = 0; i < 4; ++i) {
            int m = m0 + wv*16 + q*4 + i;
            int b = m >> 8, kpos = m & 255;
            unsigned short val = f2bf(acc[t][i] + bs);
            if (n < 512) {
                int h = n >> 6, d = n & 63;
                Kbuf[((size_t)(b*HH + h)*CL + kpos)*HD + d] = val;
            } else {
                int n2 = n - 512, h = n2 >> 6, d = n2 & 63;
                Vt[((size_t)(b*HH + h)*HD + d)*CL + kpos] = val;
            }
        }
    }
}

// ---------------- mega kernel: all 20 steps ------------------------------
// 256 blocks (1/CU) x 8 waves; block = 32 rows of batch b. Phase A: wave w
// owns head h=w for BOTH 16-row tiles -> every K/Vt/wq fragment loaded once,
// feeds 2 MFMAs. launch_bounds(512,2) -> 256-reg budget for deep load
// pipelining (round-5's (512,4) gave VGPR=64 and serialized all loads).
__global__ __launch_bounds__(512, 2) void mega_kernel(
        const unsigned short* __restrict__ Kg,   // [b*8+h][256][64]
        const unsigned short* __restrict__ Vg,   // [b*8+h][64][256]
        const float* __restrict__ noise,
        const unsigned short* __restrict__ wq,   // [512][128]
        const float* __restrict__ qbiasB,        // [20][512]
        const unsigned short* __restrict__ wo,   // [128][512]
        const float* __restrict__ bo,
        const float* __restrict__ ln_g, const float* __restrict__ ln_b,
        const unsigned short* __restrict__ f1w,  // [512][128]
        const float* __restrict__ f1_b,
        const unsigned short* __restrict__ f2w,  // [128][512]
        const float* __restrict__ f2_b,
        float* __restrict__ outp) {
    __shared__ unsigned short xS[32*136];     // 8.7 KB
    __shared__ unsigned short ctxS[32*520];   // 33.3 KB
    __shared__ unsigned short hnS[32*136];    // 8.7 KB
    __shared__ unsigned short uS[2][32*136];  // 17.4 KB
    __shared__ float redS[32*4], redS2[32*4];

    int tid = threadIdx.x, w = tid >> 6, lane = tid & 63, r = lane & 15, q = lane >> 4;
    int vblk = ((blockIdx.x & 7) << 5) | (blockIdx.x >> 3);   // same-b pairs on one XCD
    int b = vblk >> 1;
    int row0 = vblk * 32;
    int h = w;                            // phase A: one head per wave
    int tB = w & 1, cg = w >> 1;          // phase B: row-tile, col-group (cols cg*32)
    int srcA = r + ((2*q) & 3)*16;
    int srcB = r + ((2*q + 1) & 3)*16;
    int odd = (q >> 1) & 1;

    // init x from noise (phase-B ownership: rows tB*16.., cols cg*32..)
    float xf[2][4];
#pragma unroll
    for (int t = 0; t < 2; ++t)
#pragma unroll
        for (int i = 0; i < 4; ++i) {
            int rl = tB*16 + q*4 + i, col = cg*32 + t*16 + r;
            float v = noise[(size_t)(row0 + rl)*AA + col];
            xf[t][i] = v;
            xS[rl*136 + col] = f2bf(v);
        }
    __syncthreads();

    const float dt = -1.f / (float)NSTEPS;
    size_t bh = (size_t)b*HH + h;
    const unsigned short* kbase = Kg + bh*CL*HD;
    const unsigned short* vbase = Vg + bh*HD*CL;

#pragma unroll 1
    for (int s = 0; s < NSTEPS; ++s) {
        const float* qb_s = qbiasB + (size_t)s*512;

        // ========== Phase A: head h, both tiles ==========
        // Q^T-proj: A = wq rows (global, shared), B = x rows (LDS, per tile)
        f32x4 qacc0[4] = {}, qacc1[4] = {};
#pragma unroll
        for (int kk = 0; kk < 4; ++kk) {
            bf16x8 bx0 = *(const bf16x8*)&xS[(r)*136 + kk*32 + q*8];
            bf16x8 bx1 = *(const bf16x8*)&xS[(16 + r)*136 + kk*32 + q*8];
#pragma unroll
            for (int t = 0; t < 4; ++t) {
                bf16x8 a = *(const bf16x8*)(wq + (size_t)(h*HD + t*16 + r)*AA + kk*32 + q*8);
                qacc0[t] = MFMA(a, bx0, qacc0[t]);
                qacc1[t] = MFMA(a, bx1, qacc1[t]);
            }
        }
        u32 qp0[4][2], qp1[4][2];
#pragma unroll
        for (int t = 0; t < 4; ++t) {
            f32x4 qb4 = *(const f32x4*)(qb_s + h*HD + t*16 + q*4);
            qp0[t][0] = pk(qacc0[t][0] + qb4[0], qacc0[t][1] + qb4[1]);
            qp0[t][1] = pk(qacc0[t][2] + qb4[2], qacc0[t][3] + qb4[3]);
            qp1[t][0] = pk(qacc1[t][0] + qb4[0], qacc1[t][1] + qb4[1]);
            qp1[t][1] = pk(qacc1[t][2] + qb4[2], qacc1[t][3] + qb4[3]);
        }
        U8 bq0[2], bq1[2];
#pragma unroll
        for (int kd = 0; kd < 2; ++kd) {
            bq0[kd] = build_ap(qp0, kd, srcA, srcB, odd);
            bq1[kd] = build_ap(qp1, kd, srcA, srcB, odd);
        }
        // S^T: A = K rows (global, shared), B = Q per tile
        f32x4 sacc0[16] = {}, sacc1[16] = {};
#pragma unroll
        for (int t = 0; t < 16; ++t)
#pragma unroll
            for (int kd = 0; kd < 2; ++kd) {
                bf16x8 a = *(const bf16x8*)(kbase + (size_t)(t*16 + r)*HD + kd*32 + q*8);
                sacc0[t] = MFMA(a, bq0[kd].v, sacc0[t]);
                sacc1[t] = MFMA(a, bq1[kd].v, sacc1[t]);
            }
        u32 pp0[16][2], pp1[16][2];
        softmax_pack(sacc0, pp0);
        softmax_pack(sacc1, pp1);
        // PV: A = P per tile (shfl), B = Vt rows (global, shared)
        f32x4 cacc0[4] = {}, cacc1[4] = {};
#pragma unroll
        for (int kk = 0; kk < 8; ++kk) {
            U8 ap0 = build_ap(pp0, kk, srcA, srcB, odd);
            U8 ap1 = build_ap(pp1, kk, srcA, srcB, odd);
#pragma unroll
            for (int t = 0; t < 4; ++t) {
                bf16x8 bv = *(const bf16x8*)(vbase + (size_t)(t*16 + r)*CL + kk*32 + q*8);
                cacc0[t] = MFMA(ap0.v, bv, cacc0[t]);
                cacc1[t] = MFMA(ap1.v, bv, cacc1[t]);
            }
        }
#pragma unroll
        for (int t = 0; t < 4; ++t)
#pragma unroll
            for (int i = 0; i < 4; ++i) {
                ctxS[(q*4 + i)*520 + h*HD + t*16 + r]      = f2bf(cacc0[t][i]);
                ctxS[(16 + q*4 + i)*520 + h*HD + t*16 + r] = f2bf(cacc1[t][i]);
            }
        __syncthreads();   // ctx complete

        // ========== Phase B: out-proj + residual + LayerNorm ==========
        f32x4 oacc[2] = {};
#pragma unroll
        for (int kk = 0; kk < 16; ++kk) {
            bf16x8 a = *(const bf16x8*)&ctxS[(tB*16 + r)*520 + kk*32 + q*8];
#pragma unroll
            for (int t = 0; t < 2; ++t) {
                bf16x8 bw = *(const bf16x8*)(wo + (size_t)(cg*32 + t*16 + r)*EE + kk*32 + q*8);
                oacc[t] = MFMA(a, bw, oacc[t]);
            }
        }
        float hv[2][4];
#pragma unroll
        for (int t = 0; t < 2; ++t) {
            float bov = bo[cg*32 + t*16 + r];
#pragma unroll
            for (int i = 0; i < 4; ++i) hv[t][i] = oacc[t][i] + bov + xf[t][i];
        }
#pragma unroll
        for (int i = 0; i < 4; ++i) {
            float s1 = hv[0][i] + hv[1][i];
            float s2 = hv[0][i]*hv[0][i] + hv[1][i]*hv[1][i];
            s1 += __shfl_xor(s1, 1);  s2 += __shfl_xor(s2, 1);
            s1 += __shfl_xor(s1, 2);  s2 += __shfl_xor(s2, 2);
            s1 += __shfl_xor(s1, 4);  s2 += __shfl_xor(s2, 4);
            s1 += __shfl_xor(s1, 8);  s2 += __shfl_xor(s2, 8);
            if (r == 0) { redS[(tB*16 + q*4 + i)*4 + cg] = s1; redS2[(tB*16 + q*4 + i)*4 + cg] = s2; }
        }
        __syncthreads();
        float hnv[2][4];
#pragma unroll
        for (int i = 0; i < 4; ++i) {
            int row = tB*16 + q*4 + i;
            float s1 = redS [row*4+0] + redS [row*4+1] + redS [row*4+2] + redS [row*4+3];
            float s2 = redS2[row*4+0] + redS2[row*4+1] + redS2[row*4+2] + redS2[row*4+3];
            float mu = s1 * (1.f/128.f);
            float var = s2 * (1.f/128.f) - mu*mu;
            float rstd = rsqrtf(var + 1e-5f);
#pragma unroll
            for (int t = 0; t < 2; ++t) {
                int col = cg*32 + t*16 + r;
                float v = (hv[t][i] - mu) * rstd * ln_g[col] + ln_b[col];
                hnv[t][i] = v;
                hnS[row*136 + col] = f2bf(v);
            }
        }
        __syncthreads();

        // ========== FFN (chunked, double-buffered uS) ==========
        f32x4 o2[2] = {};
#pragma unroll 1
        for (int nt = 0; nt < 4; ++nt) {
            f32x4 a1[2] = {};
#pragma unroll
            for (int kk = 0; kk < 4; ++kk) {
                bf16x8 a = *(const bf16x8*)&hnS[(tB*16 + r)*136 + kk*32 + q*8];
#pragma unroll
                for (int t = 0; t < 2; ++t) {
                    bf16x8 bw = *(const bf16x8*)(f1w + (size_t)(nt*128 + cg*32 + t*16 + r)*AA + kk*32 + q*8);
                    a1[t] = MFMA(a, bw, a1[t]);
                }
            }
            unsigned short* up = uS[nt & 1];
#pragma unroll
            for (int t = 0; t < 2; ++t) {
                float b1 = f1_b[nt*128 + cg*32 + t*16 + r];
#pragma unroll
                for (int i = 0; i < 4; ++i)
                    up[(tB*16 + q*4 + i)*136 + cg*32 + t*16 + r] = f2bf(fmaxf(a1[t][i] + b1, 0.f));
            }
            __syncthreads();
#pragma unroll
            for (int kk = 0; kk < 4; ++kk) {
                bf16x8 a = *(const bf16x8*)&up[(tB*16 + r)*136 + kk*32 + q*8];
#pragma unroll
                for (int t = 0; t < 2; ++t) {
                    bf16x8 bw = *(const bf16x8*)(f2w + (size_t)(cg*32 + t*16 + r)*EE + nt*128 + kk*32 + q*8);
                    o2[t] = MFMA(a, bw, o2[t]);
                }
            }
        }

        // ========== x update ==========
        if (s < NSTEPS - 1) {
#pragma unroll
            for (int t = 0; t < 2; ++t) {
                float b2 = f2_b[cg*32 + t*16 + r];
#pragma unroll
                for (int i = 0; i < 4; ++i) {
                    float outv = hnv[t][i] + o2[t][i] + b2;
                    float xn = xf[t][i] + dt * outv;
                    xf[t][i] = xn;
                    xS[(tB*16 + q*4 + i)*136 + cg*32 + t*16 + r] = f2bf(xn);
                }
            }
            __syncthreads();   // xS ready for next step's phase A
        } else {
#pragma unroll
            for (int t = 0; t < 2; ++t) {
                float b2 = f2_b[cg*32 + t*16 + r];
#pragma unroll
                for (int i = 0; i < 4; ++i) {
                    float outv = hnv[t][i] + o2[t][i] + b2;
                    outp[(size_t)(row0 + tB*16 + q*4 + i)*AA + cg*32 + t*16 + r] = xf[t][i] + dt * outv;
                }
            }
        }
    }
}

extern "C" void kernel_launch(void* const* d_in, const int* in_sizes, int n_in,
                              void* d_out, int out_size, void* d_ws, size_t ws_size,
                              hipStream_t stream) {
    const float* cond   = (const float*)d_in[0];
    const float* noise  = (const float*)d_in[1];
    const float* t1_w   = (const float*)d_in[2];
    const float* t1_b   = (const float*)d_in[3];
    const float* t2_w   = (const float*)d_in[4];
    const float* t2_b   = (const float*)d_in[5];
    const float* qp_w   = (const float*)d_in[6];
    const float* qp_b   = (const float*)d_in[7];
    const float* in_w   = (const float*)d_in[8];
    const float* in_b   = (const float*)d_in[9];
    const float* op_w   = (const float*)d_in[10];
    const float* op_b   = (const float*)d_in[11];
    const float* outp_w = (const float*)d_in[12];
    const float* outp_b = (const float*)d_in[13];
    const float* f1_w   = (const float*)d_in[14];
    const float* f1_b   = (const float*)d_in[15];
    const float* f2_w   = (const float*)d_in[16];
    const float* f2_b   = (const float*)d_in[17];
    const float* ln_g   = (const float*)d_in[18];
    const float* ln_bp  = (const float*)d_in[19];

    char* w = (char*)d_ws;
    auto alloc = [&](size_t bytes) {
        char* p = w;
        w += (bytes + 255) & ~(size_t)255;
        return p;
    };
    unsigned short* Kbuf   = (unsigned short*)alloc((size_t)NB*HH*CL*HD*2);   // 33.5 MB
    unsigned short* Vt     = (unsigned short*)alloc((size_t)NB*HH*HD*CL*2);   // 33.5 MB
    unsigned short* condb  = (unsigned short*)alloc((size_t)NB*CL*EE*2);      // 33.5 MB
    unsigned short* wkv_bf = (unsigned short*)alloc((size_t)1024*512*2);      // 1 MB
    unsigned short* wq_bf  = (unsigned short*)alloc((size_t)512*128*2);
    unsigned short* wo_bf  = (unsigned short*)alloc((size_t)128*512*2);
    unsigned short* f1_bf  = (unsigned short*)alloc((size_t)512*128*2);
    unsigned short* f2_bf  = (unsigned short*)alloc((size_t)128*512*2);
    float*          bo_eff = (float*)alloc(128*4);
    float*          tembB  = (float*)alloc((size_t)NSTEPS*512*4);
    float*          qbiasB = (float*)alloc((size_t)NSTEPS*512*4);
    (void)ws_size; (void)n_in; (void)in_sizes; (void)out_size;

    // --- one-time prep ---
    cvt8_kernel<<<8192, 256, 0, stream>>>(cond, condb, NB*CL*EE/8);
    cvt8_kernel<<<256, 256, 0, stream>>>(in_w + 512*512, wkv_bf, 1024*512/8);
    cvt8_kernel<<<32, 256, 0, stream>>>(f1_w, f1_bf, 512*128/8);
    cvt8_kernel<<<32, 256, 0, stream>>>(f2_w, f2_bf, 128*512/8);
    prep_eff_kernel<<<513, 256, 0, stream>>>(in_w, qp_w, outp_w, op_w, op_b, outp_b,
                                             wq_bf, wo_bf, bo_eff);
    temb_kernel<<<40, 256, 0, stream>>>(t1_w, t1_b, t2_w, t2_b, tembB);
    qbias_kernel<<<40, 256, 0, stream>>>(in_w, in_b, qp_b, tembB, qbiasB);
    kv_kernel<<<2048, 512, 0, stream>>>(condb, wkv_bf, in_b + 512, Kbuf, Vt);

    // --- all 20 denoise steps, one kernel, 256 blocks x 8 waves ---
    mega_kernel<<<256, 512, 0, stream>>>(Kbuf, Vt, noise, wq_bf, qbiasB,
                                         wo_bf, bo_eff, ln_g, ln_bp,
                                         f1_bf, f1_b, f2_bf, f2_b,
                                         (float*)d_out);
}

// Round 7
// 1490.122 us; speedup vs baseline: 2.7704x; 1.2539x over previous
//
#include <hip/hip_runtime.h>

#define NB 128
#define CL 256
#define EE 512
#define AA 128
#define LL 64
#define HH 8
#define HD 64
#define NSTEPS 20
#define BLROWS (NB*LL)   // 8192
#define LOG2E 1.4426950408889634f
// Q pre-scale: keeps fp8 Q out of e4m3 subnormals; removed via 1/64 in exp2 arg
#define QSCALE 64.0f
#define INV_QS 0.015625f

typedef __attribute__((ext_vector_type(8))) short bf16x8;
typedef __attribute__((ext_vector_type(4))) float f32x4;
typedef unsigned int u32;

union F8 { u32 u[2]; long l; };   // 8-byte fp8 MFMA operand (2 VGPRs)

__device__ __forceinline__ unsigned short f2bf(float f) {
    union { float f; unsigned u; } x; x.f = f;
    unsigned u = x.u;
    u += 0x7fffu + ((u >> 16) & 1u);   // round-to-nearest-even
    return (unsigned short)(u >> 16);
}
// pack f32x4 -> 4 x fp8 e4m3 (OCP on gfx950)
__device__ __forceinline__ u32 pk4f8(f32x4 v) {
    u32 r = __builtin_amdgcn_cvt_pk_fp8_f32(v[0], v[1], 0, false);
    r = __builtin_amdgcn_cvt_pk_fp8_f32(v[2], v[3], r, true);
    return r;
}
__device__ __forceinline__ unsigned char f2f8(float v) {
    return (unsigned char)(__builtin_amdgcn_cvt_pk_fp8_f32(v, v, 0, false) & 0xffu);
}

// async global->LDS, 16B per lane
__device__ __forceinline__ void async_copy16(const unsigned short* g, unsigned short* l) {
    __builtin_amdgcn_global_load_lds((const __attribute__((address_space(1))) u32*)g,
                                     (__attribute__((address_space(3))) u32*)l, 16, 0, 0);
}

#define MFMA(a,b,c)  __builtin_amdgcn_mfma_f32_16x16x32_bf16(a, b, c, 0, 0, 0)
#define MFMA8(a,b,c) __builtin_amdgcn_mfma_f32_16x16x32_fp8_fp8(a, b, c, 0, 0, 0)

// D-layout u32-packed quads (p[t] = 4 fp8, rows t*16+q*4..+3 of the D tile)
// -> A/B-operand 8-byte frag for k-chunk kk: k = kk*32 + q*8 + jj.
// jj0-3 from quad (2q)&3, jj4-7 from quad (2q+1)&3, source reg t = 2kk + (q>>1).
__device__ __forceinline__ F8 build8(const u32* p, int kk, int srcA, int srcB, int odd) {
    u32 a0 = __shfl((int)p[2*kk],   srcA, 64);
    u32 b0 = __shfl((int)p[2*kk+1], srcA, 64);
    u32 a1 = __shfl((int)p[2*kk],   srcB, 64);
    u32 b1 = __shfl((int)p[2*kk+1], srcB, 64);
    F8 f; f.u[0] = odd ? b0 : a0; f.u[1] = odd ? b1 : a1;
    return f;
}

// softmax over 256 scores (sacc = 64*log2e-scaled scores), P packed fp8 *64
__device__ __forceinline__ void softmax8(f32x4* sacc, u32* pp8) {
    float mx = sacc[0][0];
#pragma unroll
    for (int t = 0; t < 16; ++t)
#pragma unroll
        for (int i = 0; i < 4; ++i) mx = fmaxf(mx, sacc[t][i]);
    mx = fmaxf(mx, __shfl_xor(mx, 16));
    mx = fmaxf(mx, __shfl_xor(mx, 32));
    float mxc = mx * INV_QS;
    float sum = 0.f;
#pragma unroll
    for (int t = 0; t < 16; ++t)
#pragma unroll
        for (int i = 0; i < 4; ++i) {
            float e = exp2f(fmaf(sacc[t][i], INV_QS, -mxc));
            sacc[t][i] = e; sum += e;
        }
    sum += __shfl_xor(sum, 16);
    sum += __shfl_xor(sum, 32);
    float iv = QSCALE / sum;
#pragma unroll
    for (int t = 0; t < 16; ++t) {
        f32x4 w = sacc[t];
        w[0]*=iv; w[1]*=iv; w[2]*=iv; w[3]*=iv;
        pp8[t] = pk4f8(w);
    }
}

// ---------------- prep kernels ----------------

__global__ void cvt8_kernel(const float* __restrict__ src, unsigned short* __restrict__ dst, int n8) {
    int i = blockIdx.x*256 + threadIdx.x;
    if (i >= n8) return;
    const float* s = src + (size_t)i*8;
    f32x4 v0 = *(const f32x4*)s;
    f32x4 v1 = *(const f32x4*)(s + 4);
    bf16x8 o;
    o[0]=(short)f2bf(v0[0]); o[1]=(short)f2bf(v0[1]);
    o[2]=(short)f2bf(v0[2]); o[3]=(short)f2bf(v0[3]);
    o[4]=(short)f2bf(v1[0]); o[5]=(short)f2bf(v1[1]);
    o[6]=(short)f2bf(v1[2]); o[7]=(short)f2bf(v1[3]);
    *(bf16x8*)(dst + (size_t)i*8) = o;
}

// Wq_eff = (0.125*log2e*QSCALE)*(in_w[:E] @ qp_w); Wo_eff = outp_w @ op_w; bo_eff
__global__ void prep_eff_kernel(const float* __restrict__ in_w, const float* __restrict__ qp_w,
                                const float* __restrict__ outp_w, const float* __restrict__ op_w,
                                const float* __restrict__ op_b, const float* __restrict__ outp_b,
                                unsigned short* __restrict__ wq, unsigned short* __restrict__ wo,
                                float* __restrict__ bo) {
    int tid = blockIdx.x*256 + threadIdx.x;
    if (tid < 65536) {
        int n = tid >> 7, k = tid & 127;
        float s = 0.f;
        for (int e = 0; e < 512; ++e) s += in_w[(size_t)n*512 + e] * qp_w[(size_t)e*128 + k];
        wq[(size_t)n*128 + k] = f2bf(s * (0.125f * LOG2E * QSCALE));
    } else if (tid < 131072) {
        int t2 = tid - 65536; int n = t2 >> 9, k = t2 & 511;
        float s = 0.f;
        for (int e = 0; e < 512; ++e) s += outp_w[(size_t)n*512 + e] * op_w[(size_t)e*512 + k];
        wo[(size_t)n*512 + k] = f2bf(s);
    } else if (tid < 131200) {
        int n = tid - 131072;
        float s = outp_b[n];
        for (int e = 0; e < 512; ++e) s += outp_w[(size_t)n*512 + e] * op_b[e];
        bo[n] = s;
    }
}

__global__ void temb_kernel(const float* __restrict__ t1_w, const float* __restrict__ t1_b,
                            const float* __restrict__ t2_w, const float* __restrict__ t2_b,
                            float* __restrict__ temb) {
    int tid = blockIdx.x*256 + threadIdx.x;
    if (tid >= NSTEPS*512) return;
    int s = tid >> 9, e = tid & 511;
    float t = 1.0f - 0.05f * (float)s;
    float acc = t2_b[e];
    for (int i = 0; i < 512; ++i)
        acc += t2_w[(size_t)e*512 + i] * fmaxf(t * t1_w[i] + t1_b[i], 0.f);
    temb[tid] = acc;
}

__global__ void qbias_kernel(const float* __restrict__ in_w, const float* __restrict__ in_b,
                             const float* __restrict__ qp_b, const float* __restrict__ temb,
                             float* __restrict__ qbias) {
    int tid = blockIdx.x*256 + threadIdx.x;
    if (tid >= NSTEPS*512) return;
    int s = tid >> 9, n = tid & 511;
    float acc = in_b[n];
    const float* te = temb + (size_t)s*512;
    for (int e = 0; e < 512; ++e)
        acc += in_w[(size_t)n*512 + e] * (qp_b[e] + te[e]);
    qbias[tid] = acc * (0.125f * LOG2E * QSCALE);
}

// ---------------- fused K+V projection GEMM -> fp8 K/V ----------------
// Same GEMM as round 3-6; epilogue quantizes to e4m3 and stores into
// fragment-permuted layouts so mega reads one dwordx4 per 16-row frag pair:
//   K8[bh][kpos][colp(d)],  colp = ((d>>3)&3)*16 + ((d>>5)&1)*8 + (d&7)
//   V8[bh][d][colv(kpos)],  colv = (kk>>1)*64 + qq*16 + (kk&1)*8 + jj
__global__ __launch_bounds__(512, 8) void kv_kernel(const unsigned short* __restrict__ condb,
                                                    const unsigned short* __restrict__ wkv,
                                                    const float* __restrict__ bias,
                                                    unsigned char* __restrict__ K8,
                                                    unsigned char* __restrict__ V8) {
    __shared__ unsigned short As[128*64];
    __shared__ unsigned short Bs[128*64];
    int tid = threadIdx.x;
    int blk = blockIdx.x;
    int xcd = blk & 7, j = blk >> 3;
    int m0 = (xcd*32 + (j >> 3)) * 128;
    int n0 = (j & 7) * 128;
    int wv = tid >> 6, lane = tid & 63, r = lane & 15, q = lane >> 4;
    int srow = lane >> 3;
    int sg = (lane & 7) ^ srow;
    const unsigned short* agl = condb + (size_t)(m0 + wv*16 + srow)*512 + sg*8;
    const unsigned short* bgl = wkv   + (size_t)(n0 + wv*16 + srow)*512 + sg*8;
    f32x4 acc[8] = {};
#pragma unroll
    for (int kt = 0; kt < 8; ++kt) {
        int k0 = kt * 64;
#pragma unroll
        for (int ii = 0; ii < 2; ++ii) {
            async_copy16(agl + (size_t)(ii*8)*512 + k0, &As[(wv*16 + ii*8)*64]);
            async_copy16(bgl + (size_t)(ii*8)*512 + k0, &Bs[(wv*16 + ii*8)*64]);
        }
        __syncthreads();
#pragma unroll
        for (int kk = 0; kk < 2; ++kk) {
            int gof = ((kk*4 + q) ^ (r & 7)) * 8;
            bf16x8 a = *(const bf16x8*)&As[(wv*16 + r)*64 + gof];
#pragma unroll
            for (int t = 0; t < 8; ++t) {
                bf16x8 b = *(const bf16x8*)&Bs[(t*16 + r)*64 + gof];
                acc[t] = MFMA(a, b, acc[t]);
            }
        }
        __syncthreads();
    }
    int mbase = m0 + wv*16 + q*4;
    int bb = mbase >> 8, kpb = mbase & 255;
#pragma unroll
    for (int t = 0; t < 8; ++t) {
        int n = n0 + t*16 + r;
        float bs = bias[n];
        if (n < 512) {
            int h = n >> 6, d = n & 63;
            int colp = ((d>>3)&3)*16 + ((d>>5)&1)*8 + (d&7);
            unsigned char* kp = K8 + (size_t)(bb*HH + h)*16384 + colp;
#pragma unroll
            for (int i = 0; i < 4; ++i)
                kp[(kpb + i)*64] = f2f8(acc[t][i] + bs);
        } else {
            int n2 = n - 512, h = n2 >> 6, d = n2 & 63;
            int kk = kpb >> 5, qq = (kpb >> 3) & 3, jb = kpb & 7;
            int colv = (kk>>1)*64 + qq*16 + (kk&1)*8 + jb;
            u32 w01 = __builtin_amdgcn_cvt_pk_fp8_f32(acc[t][0]+bs, acc[t][1]+bs, 0, false);
            w01 = __builtin_amdgcn_cvt_pk_fp8_f32(acc[t][2]+bs, acc[t][3]+bs, w01, true);
            *(u32*)(V8 + (size_t)(bb*HH + h)*16384 + d*256 + colv) = w01;
        }
    }
}

// ---------------- mega kernel: all 20 steps, fp8 attention ------------------
// 256 blocks (1/CU) x 8 waves; block = 32 rows of batch b; wave = head, both
// 16-row tiles. K/V are fp8 (16.4 KB per (b,h)): per-XCD working set 4.2 MB ->
// L2-resident across steps (round-6 bf16 thrashed: FETCH showed full per-step
// re-fetch). Q pre-scaled x64 (folded in wq/qbias, removed in exp2 arg);
// P scaled x64 before e4m3 pack, removed after PV.
__global__ __launch_bounds__(512, 2) void mega_kernel(
        const unsigned char* __restrict__ Kg,    // [b*8+h][256][64] fp8, col-permuted
        const unsigned char* __restrict__ Vg,    // [b*8+h][64][256] fp8, col-permuted
        const float* __restrict__ noise,
        const unsigned short* __restrict__ wq,   // [512][128] bf16 (x64 scale)
        const float* __restrict__ qbiasB,        // [20][512]  (x64 scale)
        const unsigned short* __restrict__ wo,   // [128][512]
        const float* __restrict__ bo,
        const float* __restrict__ ln_g, const float* __restrict__ ln_b,
        const unsigned short* __restrict__ f1w,  // [512][128]
        const float* __restrict__ f1_b,
        const unsigned short* __restrict__ f2w,  // [128][512]
        const float* __restrict__ f2_b,
        float* __restrict__ outp) {
    __shared__ unsigned short xS[32*136];     // 8.7 KB
    __shared__ unsigned short ctxS[32*520];   // 33.3 KB
    __shared__ unsigned short hnS[32*136];    // 8.7 KB
    __shared__ unsigned short uS[2][32*136];  // 17.4 KB
    __shared__ float redS[32*4], redS2[32*4];

    int tid = threadIdx.x, w = tid >> 6, lane = tid & 63, r = lane & 15, q = lane >> 4;
    int vblk = ((blockIdx.x & 7) << 5) | (blockIdx.x >> 3);   // same-b pairs on one XCD
    int b = vblk >> 1;
    int row0 = vblk * 32;
    int h = w;                            // phase A: one head per wave
    int tB = w & 1, cg = w >> 1;          // phase B: row-tile, col-group (cols cg*32)
    int srcA = r + ((2*q) & 3)*16;
    int srcB = r + ((2*q + 1) & 3)*16;
    int odd = (q >> 1) & 1;

    float xf[2][4];
#pragma unroll
    for (int t = 0; t < 2; ++t)
#pragma unroll
        for (int i = 0; i < 4; ++i) {
            int rl = tB*16 + q*4 + i, col = cg*32 + t*16 + r;
            float v = noise[(size_t)(row0 + rl)*AA + col];
            xf[t][i] = v;
            xS[rl*136 + col] = f2bf(v);
        }
    __syncthreads();

    const float dt = -1.f / (float)NSTEPS;
    size_t bh = (size_t)b*HH + h;
    const unsigned char* kbase = Kg + bh*16384;
    const unsigned char* vbase = Vg + bh*16384;

#pragma unroll 1
    for (int s = 0; s < NSTEPS; ++s) {
        const float* qb_s = qbiasB + (size_t)s*512;

        // ===== Phase A: Q-proj (bf16) =====
        f32x4 qacc0[4] = {}, qacc1[4] = {};
#pragma unroll
        for (int kk = 0; kk < 4; ++kk) {
            bf16x8 bx0 = *(const bf16x8*)&xS[(r)*136 + kk*32 + q*8];
            bf16x8 bx1 = *(const bf16x8*)&xS[(16 + r)*136 + kk*32 + q*8];
#pragma unroll
            for (int t = 0; t < 4; ++t) {
                bf16x8 a = *(const bf16x8*)(wq + (size_t)(h*HD + t*16 + r)*AA + kk*32 + q*8);
                qacc0[t] = MFMA(a, bx0, qacc0[t]);
                qacc1[t] = MFMA(a, bx1, qacc1[t]);
            }
        }
        u32 qp0[4], qp1[4];
#pragma unroll
        for (int t = 0; t < 4; ++t) {
            f32x4 qb4 = *(const f32x4*)(qb_s + h*HD + t*16 + q*4);
            f32x4 v0, v1;
#pragma unroll
            for (int i = 0; i < 4; ++i) { v0[i] = qacc0[t][i] + qb4[i]; v1[i] = qacc1[t][i] + qb4[i]; }
            qp0[t] = pk4f8(v0);
            qp1[t] = pk4f8(v1);
        }
        F8 bq0[2], bq1[2];
#pragma unroll
        for (int kd = 0; kd < 2; ++kd) {
            bq0[kd] = build8(qp0, kd, srcA, srcB, odd);
            bq1[kd] = build8(qp1, kd, srcA, srcB, odd);
        }
        // ===== S^T fp8: one 16B load covers both kd frags (permuted layout) =====
        f32x4 sacc0[16] = {}, sacc1[16] = {};
#pragma unroll
        for (int t = 0; t < 16; ++t) {
            uint4 kf = *(const uint4*)(kbase + (size_t)(t*16 + r)*64 + q*16);
            F8 k0, k1;
            k0.u[0] = kf.x; k0.u[1] = kf.y;
            k1.u[0] = kf.z; k1.u[1] = kf.w;
            sacc0[t] = MFMA8(k0.l, bq0[0].l, sacc0[t]);
            sacc0[t] = MFMA8(k1.l, bq0[1].l, sacc0[t]);
            sacc1[t] = MFMA8(k0.l, bq1[0].l, sacc1[t]);
            sacc1[t] = MFMA8(k1.l, bq1[1].l, sacc1[t]);
        }
        u32 pp0[16], pp1[16];
        softmax8(sacc0, pp0);
        softmax8(sacc1, pp1);
        // ===== PV fp8: 16B V load covers kk-pair frags (permuted layout) =====
        f32x4 cacc0[4] = {}, cacc1[4] = {};
#pragma unroll
        for (int kp = 0; kp < 4; ++kp) {
            F8 a00 = build8(pp0, 2*kp,   srcA, srcB, odd);
            F8 a01 = build8(pp0, 2*kp+1, srcA, srcB, odd);
            F8 a10 = build8(pp1, 2*kp,   srcA, srcB, odd);
            F8 a11 = build8(pp1, 2*kp+1, srcA, srcB, odd);
#pragma unroll
            for (int t = 0; t < 4; ++t) {
                uint4 vf = *(const uint4*)(vbase + (size_t)(t*16 + r)*256 + kp*64 + q*16);
                F8 v0, v1;
                v0.u[0] = vf.x; v0.u[1] = vf.y;
                v1.u[0] = vf.z; v1.u[1] = vf.w;
                cacc0[t] = MFMA8(a00.l, v0.l, cacc0[t]);
                cacc0[t] = MFMA8(a01.l, v1.l, cacc0[t]);
                cacc1[t] = MFMA8(a10.l, v0.l, cacc1[t]);
                cacc1[t] = MFMA8(a11.l, v1.l, cacc1[t]);
            }
        }
#pragma unroll
        for (int t = 0; t < 4; ++t)
#pragma unroll
            for (int i = 0; i < 4; ++i) {
                ctxS[(q*4 + i)*520 + h*HD + t*16 + r]      = f2bf(cacc0[t][i] * INV_QS);
                ctxS[(16 + q*4 + i)*520 + h*HD + t*16 + r] = f2bf(cacc1[t][i] * INV_QS);
            }
        __syncthreads();   // ctx complete

        // ===== Phase B: out-proj + residual + LayerNorm (bf16, unchanged) =====
        f32x4 oacc[2] = {};
#pragma unroll
        for (int kk = 0; kk < 16; ++kk) {
            bf16x8 a = *(const bf16x8*)&ctxS[(tB*16 + r)*520 + kk*32 + q*8];
#pragma unroll
            for (int t = 0; t < 2; ++t) {
                bf16x8 bw = *(const bf16x8*)(wo + (size_t)(cg*32 + t*16 + r)*EE + kk*32 + q*8);
                oacc[t] = MFMA(a, bw, oacc[t]);
            }
        }
        float hv[2][4];
#pragma unroll
        for (int t = 0; t < 2; ++t) {
            float bov = bo[cg*32 + t*16 + r];
#pragma unroll
            for (int i = 0; i < 4; ++i) hv[t][i] = oacc[t][i] + bov + xf[t][i];
        }
#pragma unroll
        for (int i = 0; i < 4; ++i) {
            float s1 = hv[0][i] + hv[1][i];
            float s2 = hv[0][i]*hv[0][i] + hv[1][i]*hv[1][i];
            s1 += __shfl_xor(s1, 1);  s2 += __shfl_xor(s2, 1);
            s1 += __shfl_xor(s1, 2);  s2 += __shfl_xor(s2, 2);
            s1 += __shfl_xor(s1, 4);  s2 += __shfl_xor(s2, 4);
            s1 += __shfl_xor(s1, 8);  s2 += __shfl_xor(s2, 8);
            if (r == 0) { redS[(tB*16 + q*4 + i)*4 + cg] = s1; redS2[(tB*16 + q*4 + i)*4 + cg] = s2; }
        }
        __syncthreads();
        float hnv[2][4];
#pragma unroll
        for (int i = 0; i < 4; ++i) {
            int row = tB*16 + q*4 + i;
            float s1 = redS [row*4+0] + redS [row*4+1] + redS [row*4+2] + redS [row*4+3];
            float s2 = redS2[row*4+0] + redS2[row*4+1] + redS2[row*4+2] + redS2[row*4+3];
            float mu = s1 * (1.f/128.f);
            float var = s2 * (1.f/128.f) - mu*mu;
            float rstd = rsqrtf(var + 1e-5f);
#pragma unroll
            for (int t = 0; t < 2; ++t) {
                int col = cg*32 + t*16 + r;
                float v = (hv[t][i] - mu) * rstd * ln_g[col] + ln_b[col];
                hnv[t][i] = v;
                hnS[row*136 + col] = f2bf(v);
            }
        }
        __syncthreads();

        // ===== FFN (chunked, double-buffered uS) =====
        f32x4 o2[2] = {};
#pragma unroll 1
        for (int nt = 0; nt < 4; ++nt) {
            f32x4 a1[2] = {};
#pragma unroll
            for (int kk = 0; kk < 4; ++kk) {
                bf16x8 a = *(const bf16x8*)&hnS[(tB*16 + r)*136 + kk*32 + q*8];
#pragma unroll
                for (int t = 0; t < 2; ++t) {
                    bf16x8 bw = *(const bf16x8*)(f1w + (size_t)(nt*128 + cg*32 + t*16 + r)*AA + kk*32 + q*8);
                    a1[t] = MFMA(a, bw, a1[t]);
                }
            }
            unsigned short* up = uS[nt & 1];
#pragma unroll
            for (int t = 0; t < 2; ++t) {
                float b1 = f1_b[nt*128 + cg*32 + t*16 + r];
#pragma unroll
                for (int i = 0; i < 4; ++i)
                    up[(tB*16 + q*4 + i)*136 + cg*32 + t*16 + r] = f2bf(fmaxf(a1[t][i] + b1, 0.f));
            }
            __syncthreads();
#pragma unroll
            for (int kk = 0; kk < 4; ++kk) {
                bf16x8 a = *(const bf16x8*)&up[(tB*16 + r)*136 + kk*32 + q*8];
#pragma unroll
                for (int t = 0; t < 2; ++t) {
                    bf16x8 bw = *(const bf16x8*)(f2w + (size_t)(cg*32 + t*16 + r)*EE + nt*128 + kk*32 + q*8);
                    o2[t] = MFMA(a, bw, o2[t]);
                }
            }
        }

        // ===== x update =====
        if (s < NSTEPS - 1) {
#pragma unroll
            for (int t = 0; t < 2; ++t) {
                float b2 = f2_b[cg*32 + t*16 + r];
#pragma unroll
                for (int i = 0; i < 4; ++i) {
                    float outv = hnv[t][i] + o2[t][i] + b2;
                    float xn = xf[t][i] + dt * outv;
                    xf[t][i] = xn;
                    xS[(tB*16 + q*4 + i)*136 + cg*32 + t*16 + r] = f2bf(xn);
                }
            }
            __syncthreads();   // xS ready for next step's phase A
        } else {
#pragma unroll
            for (int t = 0; t < 2; ++t) {
                float b2 = f2_b[cg*32 + t*16 + r];
#pragma unroll
                for (int i = 0; i < 4; ++i) {
                    float outv = hnv[t][i] + o2[t][i] + b2;
                    outp[(size_t)(row0 + tB*16 + q*4 + i)*AA + cg*32 + t*16 + r] = xf[t][i] + dt * outv;
                }
            }
        }
    }
}

extern "C" void kernel_launch(void* const* d_in, const int* in_sizes, int n_in,
                              void* d_out, int out_size, void* d_ws, size_t ws_size,
                              hipStream_t stream) {
    const float* cond   = (const float*)d_in[0];
    const float* noise  = (const float*)d_in[1];
    const float* t1_w   = (const float*)d_in[2];
    const float* t1_b   = (const float*)d_in[3];
    const float* t2_w   = (const float*)d_in[4];
    const float* t2_b   = (const float*)d_in[5];
    const float* qp_w   = (const float*)d_in[6];
    const float* qp_b   = (const float*)d_in[7];
    const float* in_w   = (const float*)d_in[8];
    const float* in_b   = (const float*)d_in[9];
    const float* op_w   = (const float*)d_in[10];
    const float* op_b   = (const float*)d_in[11];
    const float* outp_w = (const float*)d_in[12];
    const float* outp_b = (const float*)d_in[13];
    const float* f1_w   = (const float*)d_in[14];
    const float* f1_b   = (const float*)d_in[15];
    const float* f2_w   = (const float*)d_in[16];
    const float* f2_b   = (const float*)d_in[17];
    const float* ln_g   = (const float*)d_in[18];
    const float* ln_bp  = (const float*)d_in[19];

    char* w = (char*)d_ws;
    auto alloc = [&](size_t bytes) {
        char* p = w;
        w += (bytes + 255) & ~(size_t)255;
        return p;
    };
    unsigned char*  K8     = (unsigned char*)alloc((size_t)NB*HH*CL*HD);      // 16.8 MB fp8
    unsigned char*  V8     = (unsigned char*)alloc((size_t)NB*HH*HD*CL);      // 16.8 MB fp8
    unsigned short* condb  = (unsigned short*)alloc((size_t)NB*CL*EE*2);      // 33.5 MB
    unsigned short* wkv_bf = (unsigned short*)alloc((size_t)1024*512*2);      // 1 MB
    unsigned short* wq_bf  = (unsigned short*)alloc((size_t)512*128*2);
    unsigned short* wo_bf  = (unsigned short*)alloc((size_t)128*512*2);
    unsigned short* f1_bf  = (unsigned short*)alloc((size_t)512*128*2);
    unsigned short* f2_bf  = (unsigned short*)alloc((size_t)128*512*2);
    float*          bo_eff = (float*)alloc(128*4);
    float*          tembB  = (float*)alloc((size_t)NSTEPS*512*4);
    float*          qbiasB = (float*)alloc((size_t)NSTEPS*512*4);
    (void)ws_size; (void)n_in; (void)in_sizes; (void)out_size;

    // --- one-time prep ---
    cvt8_kernel<<<8192, 256, 0, stream>>>(cond, condb, NB*CL*EE/8);
    cvt8_kernel<<<256, 256, 0, stream>>>(in_w + 512*512, wkv_bf, 1024*512/8);
    cvt8_kernel<<<32, 256, 0, stream>>>(f1_w, f1_bf, 512*128/8);
    cvt8_kernel<<<32, 256, 0, stream>>>(f2_w, f2_bf, 128*512/8);
    prep_eff_kernel<<<513, 256, 0, stream>>>(in_w, qp_w, outp_w, op_w, op_b, outp_b,
                                             wq_bf, wo_bf, bo_eff);
    temb_kernel<<<40, 256, 0, stream>>>(t1_w, t1_b, t2_w, t2_b, tembB);
    qbias_kernel<<<40, 256, 0, stream>>>(in_w, in_b, qp_b, tembB, qbiasB);
    kv_kernel<<<2048, 512, 0, stream>>>(condb, wkv_bf, in_b + 512, K8, V8);

    // --- all 20 denoise steps, one kernel, 256 blocks x 8 waves ---
    mega_kernel<<<256, 512, 0, stream>>>(K8, V8, noise, wq_bf, qbiasB,
                                         wo_bf, bo_eff, ln_g, ln_bp,
                                         f1_bf, f1_b, f2_bf, f2_b,
                                         (float*)d_out);
}

// Round 8
// 1341.496 us; speedup vs baseline: 3.0774x; 1.1108x over previous
//
#include <hip/hip_runtime.h>

#define NB 128
#define CL 256
#define EE 512
#define AA 128
#define LL 64
#define HH 8
#define HD 64
#define NSTEPS 20
#define BLROWS (NB*LL)   // 8192
#define LOG2E 1.4426950408889634f
// Q pre-scale: keeps fp8 Q out of e4m3 subnormals; removed via 1/64 in exp2 arg
#define QSCALE 64.0f
#define INV_QS 0.015625f

typedef __attribute__((ext_vector_type(8))) short bf16x8;
typedef __attribute__((ext_vector_type(4))) float f32x4;
typedef unsigned int u32;

union F8 { u32 u[2]; long l; };   // 8-byte fp8 MFMA operand (2 VGPRs)

__device__ __forceinline__ unsigned short f2bf(float f) {
    union { float f; unsigned u; } x; x.f = f;
    unsigned u = x.u;
    u += 0x7fffu + ((u >> 16) & 1u);   // round-to-nearest-even
    return (unsigned short)(u >> 16);
}
// pack f32x4 -> 4 x fp8 e4m3 (OCP on gfx950)
__device__ __forceinline__ u32 pk4f8(f32x4 v) {
    u32 r = __builtin_amdgcn_cvt_pk_fp8_f32(v[0], v[1], 0, false);
    r = __builtin_amdgcn_cvt_pk_fp8_f32(v[2], v[3], r, true);
    return r;
}
__device__ __forceinline__ unsigned char f2f8(float v) {
    return (unsigned char)(__builtin_amdgcn_cvt_pk_fp8_f32(v, v, 0, false) & 0xffu);
}

// async global->LDS, 16B per lane
__device__ __forceinline__ void async_copy16(const unsigned short* g, unsigned short* l) {
    __builtin_amdgcn_global_load_lds((const __attribute__((address_space(1))) u32*)g,
                                     (__attribute__((address_space(3))) u32*)l, 16, 0, 0);
}

#define MFMA(a,b,c)  __builtin_amdgcn_mfma_f32_16x16x32_bf16(a, b, c, 0, 0, 0)
#define MFMA8(a,b,c) __builtin_amdgcn_mfma_f32_16x16x32_fp8_fp8(a, b, c, 0, 0, 0)

// D-layout u32-packed quads -> A/B-operand 8-byte frag (verified rounds 4-7)
__device__ __forceinline__ F8 build8(const u32* p, int kk, int srcA, int srcB, int odd) {
    u32 a0 = __shfl((int)p[2*kk],   srcA, 64);
    u32 b0 = __shfl((int)p[2*kk+1], srcA, 64);
    u32 a1 = __shfl((int)p[2*kk],   srcB, 64);
    u32 b1 = __shfl((int)p[2*kk+1], srcB, 64);
    F8 f; f.u[0] = odd ? b0 : a0; f.u[1] = odd ? b1 : a1;
    return f;
}

// softmax over 256 scores (sacc = 64*log2e-scaled scores), P packed fp8 *64
__device__ __forceinline__ void softmax8(f32x4* sacc, u32* pp8) {
    float mx = sacc[0][0];
#pragma unroll
    for (int t = 0; t < 16; ++t)
#pragma unroll
        for (int i = 0; i < 4; ++i) mx = fmaxf(mx, sacc[t][i]);
    mx = fmaxf(mx, __shfl_xor(mx, 16));
    mx = fmaxf(mx, __shfl_xor(mx, 32));
    float mxc = mx * INV_QS;
    float sum = 0.f;
#pragma unroll
    for (int t = 0; t < 16; ++t)
#pragma unroll
        for (int i = 0; i < 4; ++i) {
            float e = exp2f(fmaf(sacc[t][i], INV_QS, -mxc));
            sacc[t][i] = e; sum += e;
        }
    sum += __shfl_xor(sum, 16);
    sum += __shfl_xor(sum, 32);
    float iv = QSCALE / sum;
#pragma unroll
    for (int t = 0; t < 16; ++t) {
        f32x4 w = sacc[t];
        w[0]*=iv; w[1]*=iv; w[2]*=iv; w[3]*=iv;
        pp8[t] = pk4f8(w);
    }
}

// ---------------- prep kernels ----------------

__global__ void cvt8_kernel(const float* __restrict__ src, unsigned short* __restrict__ dst, int n8) {
    int i = blockIdx.x*256 + threadIdx.x;
    if (i >= n8) return;
    const float* s = src + (size_t)i*8;
    f32x4 v0 = *(const f32x4*)s;
    f32x4 v1 = *(const f32x4*)(s + 4);
    bf16x8 o;
    o[0]=(short)f2bf(v0[0]); o[1]=(short)f2bf(v0[1]);
    o[2]=(short)f2bf(v0[2]); o[3]=(short)f2bf(v0[3]);
    o[4]=(short)f2bf(v1[0]); o[5]=(short)f2bf(v1[1]);
    o[6]=(short)f2bf(v1[2]); o[7]=(short)f2bf(v1[3]);
    *(bf16x8*)(dst + (size_t)i*8) = o;
}

// Wq_eff = (0.125*log2e*QSCALE)*(in_w[:E] @ qp_w); Wo_eff = outp_w @ op_w; bo_eff
__global__ void prep_eff_kernel(const float* __restrict__ in_w, const float* __restrict__ qp_w,
                                const float* __restrict__ outp_w, const float* __restrict__ op_w,
                                const float* __restrict__ op_b, const float* __restrict__ outp_b,
                                unsigned short* __restrict__ wq, unsigned short* __restrict__ wo,
                                float* __restrict__ bo) {
    int tid = blockIdx.x*256 + threadIdx.x;
    if (tid < 65536) {
        int n = tid >> 7, k = tid & 127;
        float s = 0.f;
        for (int e = 0; e < 512; ++e) s += in_w[(size_t)n*512 + e] * qp_w[(size_t)e*128 + k];
        wq[(size_t)n*128 + k] = f2bf(s * (0.125f * LOG2E * QSCALE));
    } else if (tid < 131072) {
        int t2 = tid - 65536; int n = t2 >> 9, k = t2 & 511;
        float s = 0.f;
        for (int e = 0; e < 512; ++e) s += outp_w[(size_t)n*512 + e] * op_w[(size_t)e*512 + k];
        wo[(size_t)n*512 + k] = f2bf(s);
    } else if (tid < 131200) {
        int n = tid - 131072;
        float s = outp_b[n];
        for (int e = 0; e < 512; ++e) s += outp_w[(size_t)n*512 + e] * op_b[e];
        bo[n] = s;
    }
}

__global__ void temb_kernel(const float* __restrict__ t1_w, const float* __restrict__ t1_b,
                            const float* __restrict__ t2_w, const float* __restrict__ t2_b,
                            float* __restrict__ temb) {
    int tid = blockIdx.x*256 + threadIdx.x;
    if (tid >= NSTEPS*512) return;
    int s = tid >> 9, e = tid & 511;
    float t = 1.0f - 0.05f * (float)s;
    float acc = t2_b[e];
    for (int i = 0; i < 512; ++i)
        acc += t2_w[(size_t)e*512 + i] * fmaxf(t * t1_w[i] + t1_b[i], 0.f);
    temb[tid] = acc;
}

__global__ void qbias_kernel(const float* __restrict__ in_w, const float* __restrict__ in_b,
                             const float* __restrict__ qp_b, const float* __restrict__ temb,
                             float* __restrict__ qbias) {
    int tid = blockIdx.x*256 + threadIdx.x;
    if (tid >= NSTEPS*512) return;
    int s = tid >> 9, n = tid & 511;
    float acc = in_b[n];
    const float* te = temb + (size_t)s*512;
    for (int e = 0; e < 512; ++e)
        acc += in_w[(size_t)n*512 + e] * (qp_b[e] + te[e]);
    qbias[tid] = acc * (0.125f * LOG2E * QSCALE);
}

// ---------------- fused K+V projection GEMM -> fp8 K/V (unchanged) --------
__global__ __launch_bounds__(512, 8) void kv_kernel(const unsigned short* __restrict__ condb,
                                                    const unsigned short* __restrict__ wkv,
                                                    const float* __restrict__ bias,
                                                    unsigned char* __restrict__ K8,
                                                    unsigned char* __restrict__ V8) {
    __shared__ unsigned short As[128*64];
    __shared__ unsigned short Bs[128*64];
    int tid = threadIdx.x;
    int blk = blockIdx.x;
    int xcd = blk & 7, j = blk >> 3;
    int m0 = (xcd*32 + (j >> 3)) * 128;
    int n0 = (j & 7) * 128;
    int wv = tid >> 6, lane = tid & 63, r = lane & 15, q = lane >> 4;
    int srow = lane >> 3;
    int sg = (lane & 7) ^ srow;
    const unsigned short* agl = condb + (size_t)(m0 + wv*16 + srow)*512 + sg*8;
    const unsigned short* bgl = wkv   + (size_t)(n0 + wv*16 + srow)*512 + sg*8;
    f32x4 acc[8] = {};
#pragma unroll
    for (int kt = 0; kt < 8; ++kt) {
        int k0 = kt * 64;
#pragma unroll
        for (int ii = 0; ii < 2; ++ii) {
            async_copy16(agl + (size_t)(ii*8)*512 + k0, &As[(wv*16 + ii*8)*64]);
            async_copy16(bgl + (size_t)(ii*8)*512 + k0, &Bs[(wv*16 + ii*8)*64]);
        }
        __syncthreads();
#pragma unroll
        for (int kk = 0; kk < 2; ++kk) {
            int gof = ((kk*4 + q) ^ (r & 7)) * 8;
            bf16x8 a = *(const bf16x8*)&As[(wv*16 + r)*64 + gof];
#pragma unroll
            for (int t = 0; t < 8; ++t) {
                bf16x8 b = *(const bf16x8*)&Bs[(t*16 + r)*64 + gof];
                acc[t] = MFMA(a, b, acc[t]);
            }
        }
        __syncthreads();
    }
    int mbase = m0 + wv*16 + q*4;
    int bb = mbase >> 8, kpb = mbase & 255;
#pragma unroll
    for (int t = 0; t < 8; ++t) {
        int n = n0 + t*16 + r;
        float bs = bias[n];
        if (n < 512) {
            int h = n >> 6, d = n & 63;
            int colp = ((d>>3)&3)*16 + ((d>>5)&1)*8 + (d&7);
            unsigned char* kp = K8 + (size_t)(bb*HH + h)*16384 + colp;
#pragma unroll
            for (int i = 0; i < 4; ++i)
                kp[(kpb + i)*64] = f2f8(acc[t][i] + bs);
        } else {
            int n2 = n - 512, h = n2 >> 6, d = n2 & 63;
            int kk = kpb >> 5, qq = (kpb >> 3) & 3, jb = kpb & 7;
            int colv = (kk>>1)*64 + qq*16 + (kk&1)*8 + jb;
            u32 w01 = __builtin_amdgcn_cvt_pk_fp8_f32(acc[t][0]+bs, acc[t][1]+bs, 0, false);
            w01 = __builtin_amdgcn_cvt_pk_fp8_f32(acc[t][2]+bs, acc[t][3]+bs, w01, true);
            *(u32*)(V8 + (size_t)(bb*HH + h)*16384 + d*256 + colv) = w01;
        }
    }
}

// ---------------- mega kernel: all 20 steps, K/V pinned in registers -------
// 256 blocks (1/CU) x 8 waves; wave = head, both 16-row tiles (sequential).
// The wave's (b,h) fp8 K+V fragments (16+16 uint4 = 128 VGPRs) are loaded
// ONCE before the step loop -> zero K/V memory traffic during the 20 steps.
// Phase A is tile-sequential so peak live regs fit the 256 budget at 8 w/CU.
// ctxS and uS share one LDS buffer (ctx reads finish before first FFN write).
__global__ __launch_bounds__(512, 2) void mega_kernel(
        const unsigned char* __restrict__ Kg,    // [b*8+h][256][64] fp8, col-permuted
        const unsigned char* __restrict__ Vg,    // [b*8+h][64][256] fp8, col-permuted
        const float* __restrict__ noise,
        const unsigned short* __restrict__ wq,   // [512][128] bf16 (x64*log2e scale)
        const float* __restrict__ qbiasB,        // [20][512]
        const unsigned short* __restrict__ wo,   // [128][512]
        const float* __restrict__ bo,
        const float* __restrict__ ln_g, const float* __restrict__ ln_b,
        const unsigned short* __restrict__ f1w,  // [512][128]
        const float* __restrict__ f1_b,
        const unsigned short* __restrict__ f2w,  // [128][512]
        const float* __restrict__ f2_b,
        float* __restrict__ outp) {
    __shared__ unsigned short xS[32*136];     // 8.7 KB
    __shared__ unsigned short cuS[32*520];    // 33.3 KB: ctx, then u double-buffer
    __shared__ unsigned short hnS[32*136];    // 8.7 KB
    __shared__ float redS[32*4], redS2[32*4];

    int tid = threadIdx.x, w = tid >> 6, lane = tid & 63, r = lane & 15, q = lane >> 4;
    int vblk = ((blockIdx.x & 7) << 5) | (blockIdx.x >> 3);   // same-b pairs on one XCD
    int b = vblk >> 1;
    int row0 = vblk * 32;
    int h = w;                            // phase A: one head per wave
    int tB = w & 1, cg = w >> 1;          // phase B: row-tile, col-group (cols cg*32)
    int srcA = r + ((2*q) & 3)*16;
    int srcB = r + ((2*q + 1) & 3)*16;
    int odd = (q >> 1) & 1;

    float xf[2][4];
#pragma unroll
    for (int t = 0; t < 2; ++t)
#pragma unroll
        for (int i = 0; i < 4; ++i) {
            int rl = tB*16 + q*4 + i, col = cg*32 + t*16 + r;
            float v = noise[(size_t)(row0 + rl)*AA + col];
            xf[t][i] = v;
            xS[rl*136 + col] = f2bf(v);
        }

    // ---- pin K/V fragments in registers (128 VGPRs, live all 20 steps) ----
    size_t bh = (size_t)b*HH + h;
    const unsigned char* kbase = Kg + bh*16384;
    const unsigned char* vbase = Vg + bh*16384;
    uint4 kfr[16], vfr[16];
#pragma unroll
    for (int t = 0; t < 16; ++t)
        kfr[t] = *(const uint4*)(kbase + (size_t)(t*16 + r)*64 + q*16);
#pragma unroll
    for (int kp = 0; kp < 4; ++kp)
#pragma unroll
        for (int t = 0; t < 4; ++t)
            vfr[kp*4 + t] = *(const uint4*)(vbase + (size_t)(t*16 + r)*256 + kp*64 + q*16);
    __syncthreads();

    const float dt = -1.f / (float)NSTEPS;

#pragma unroll 1
    for (int s = 0; s < NSTEPS; ++s) {
        const float* qb_s = qbiasB + (size_t)s*512;

        // ===== Phase A: head h, tiles sequential (keeps sacc at 64 regs) =====
#pragma unroll 1
        for (int tile = 0; tile < 2; ++tile) {
            // Q-proj (bf16): A = wq rows (global, L2-hot), B = x rows (LDS)
            f32x4 qacc[4] = {};
#pragma unroll
            for (int kk = 0; kk < 4; ++kk) {
                bf16x8 bx = *(const bf16x8*)&xS[(tile*16 + r)*136 + kk*32 + q*8];
#pragma unroll
                for (int t = 0; t < 4; ++t) {
                    bf16x8 a = *(const bf16x8*)(wq + (size_t)(h*HD + t*16 + r)*AA + kk*32 + q*8);
                    qacc[t] = MFMA(a, bx, qacc[t]);
                }
            }
            u32 qp[4];
#pragma unroll
            for (int t = 0; t < 4; ++t) {
                f32x4 qb4 = *(const f32x4*)(qb_s + h*HD + t*16 + q*4);
                f32x4 v;
#pragma unroll
                for (int i = 0; i < 4; ++i) v[i] = qacc[t][i] + qb4[i];
                qp[t] = pk4f8(v);
            }
            F8 bq[2];
            bq[0] = build8(qp, 0, srcA, srcB, odd);
            bq[1] = build8(qp, 1, srcA, srcB, odd);
            // S^T fp8: K from pinned regs
            f32x4 sacc[16] = {};
#pragma unroll
            for (int t = 0; t < 16; ++t) {
                F8 k0, k1;
                k0.u[0] = kfr[t].x; k0.u[1] = kfr[t].y;
                k1.u[0] = kfr[t].z; k1.u[1] = kfr[t].w;
                sacc[t] = MFMA8(k0.l, bq[0].l, sacc[t]);
                sacc[t] = MFMA8(k1.l, bq[1].l, sacc[t]);
            }
            u32 pp[16];
            softmax8(sacc, pp);
            // PV fp8: V from pinned regs
            f32x4 cacc[4] = {};
#pragma unroll
            for (int kp = 0; kp < 4; ++kp) {
                F8 a0 = build8(pp, 2*kp,   srcA, srcB, odd);
                F8 a1 = build8(pp, 2*kp+1, srcA, srcB, odd);
#pragma unroll
                for (int t = 0; t < 4; ++t) {
                    F8 v0, v1;
                    v0.u[0] = vfr[kp*4+t].x; v0.u[1] = vfr[kp*4+t].y;
                    v1.u[0] = vfr[kp*4+t].z; v1.u[1] = vfr[kp*4+t].w;
                    cacc[t] = MFMA8(a0.l, v0.l, cacc[t]);
                    cacc[t] = MFMA8(a1.l, v1.l, cacc[t]);
                }
            }
#pragma unroll
            for (int t = 0; t < 4; ++t)
#pragma unroll
                for (int i = 0; i < 4; ++i)
                    cuS[(tile*16 + q*4 + i)*520 + h*HD + t*16 + r] = f2bf(cacc[t][i] * INV_QS);
        }
        __syncthreads();   // ctx complete

        // ===== Phase B: out-proj + residual + LayerNorm =====
        f32x4 oacc[2] = {};
#pragma unroll
        for (int kk = 0; kk < 16; ++kk) {
            bf16x8 a = *(const bf16x8*)&cuS[(tB*16 + r)*520 + kk*32 + q*8];
#pragma unroll
            for (int t = 0; t < 2; ++t) {
                bf16x8 bw = *(const bf16x8*)(wo + (size_t)(cg*32 + t*16 + r)*EE + kk*32 + q*8);
                oacc[t] = MFMA(a, bw, oacc[t]);
            }
        }
        float hv[2][4];
#pragma unroll
        for (int t = 0; t < 2; ++t) {
            float bov = bo[cg*32 + t*16 + r];
#pragma unroll
            for (int i = 0; i < 4; ++i) hv[t][i] = oacc[t][i] + bov + xf[t][i];
        }
#pragma unroll
        for (int i = 0; i < 4; ++i) {
            float s1 = hv[0][i] + hv[1][i];
            float s2 = hv[0][i]*hv[0][i] + hv[1][i]*hv[1][i];
            s1 += __shfl_xor(s1, 1);  s2 += __shfl_xor(s2, 1);
            s1 += __shfl_xor(s1, 2);  s2 += __shfl_xor(s2, 2);
            s1 += __shfl_xor(s1, 4);  s2 += __shfl_xor(s2, 4);
            s1 += __shfl_xor(s1, 8);  s2 += __shfl_xor(s2, 8);
            if (r == 0) { redS[(tB*16 + q*4 + i)*4 + cg] = s1; redS2[(tB*16 + q*4 + i)*4 + cg] = s2; }
        }
        __syncthreads();   // also: all ctx reads from cuS are done after this
        float hnv[2][4];
#pragma unroll
        for (int i = 0; i < 4; ++i) {
            int row = tB*16 + q*4 + i;
            float s1 = redS [row*4+0] + redS [row*4+1] + redS [row*4+2] + redS [row*4+3];
            float s2 = redS2[row*4+0] + redS2[row*4+1] + redS2[row*4+2] + redS2[row*4+3];
            float mu = s1 * (1.f/128.f);
            float var = s2 * (1.f/128.f) - mu*mu;
            float rstd = rsqrtf(var + 1e-5f);
#pragma unroll
            for (int t = 0; t < 2; ++t) {
                int col = cg*32 + t*16 + r;
                float v = (hv[t][i] - mu) * rstd * ln_g[col] + ln_b[col];
                hnv[t][i] = v;
                hnS[row*136 + col] = f2bf(v);
            }
        }
        __syncthreads();

        // ===== FFN (chunked; u double-buffer aliased into cuS) =====
        f32x4 o2[2] = {};
#pragma unroll 1
        for (int nt = 0; nt < 4; ++nt) {
            f32x4 a1[2] = {};
#pragma unroll
            for (int kk = 0; kk < 4; ++kk) {
                bf16x8 a = *(const bf16x8*)&hnS[(tB*16 + r)*136 + kk*32 + q*8];
#pragma unroll
                for (int t = 0; t < 2; ++t) {
                    bf16x8 bw = *(const bf16x8*)(f1w + (size_t)(nt*128 + cg*32 + t*16 + r)*AA + kk*32 + q*8);
                    a1[t] = MFMA(a, bw, a1[t]);
                }
            }
            unsigned short* up = cuS + (nt & 1)*(32*136);
#pragma unroll
            for (int t = 0; t < 2; ++t) {
                float b1 = f1_b[nt*128 + cg*32 + t*16 + r];
#pragma unroll
                for (int i = 0; i < 4; ++i)
                    up[(tB*16 + q*4 + i)*136 + cg*32 + t*16 + r] = f2bf(fmaxf(a1[t][i] + b1, 0.f));
            }
            __syncthreads();
#pragma unroll
            for (int kk = 0; kk < 4; ++kk) {
                bf16x8 a = *(const bf16x8*)&up[(tB*16 + r)*136 + kk*32 + q*8];
#pragma unroll
                for (int t = 0; t < 2; ++t) {
                    bf16x8 bw = *(const bf16x8*)(f2w + (size_t)(cg*32 + t*16 + r)*EE + nt*128 + kk*32 + q*8);
                    o2[t] = MFMA(a, bw, o2[t]);
                }
            }
        }

        // ===== x update =====
        if (s < NSTEPS - 1) {
#pragma unroll
            for (int t = 0; t < 2; ++t) {
                float b2 = f2_b[cg*32 + t*16 + r];
#pragma unroll
                for (int i = 0; i < 4; ++i) {
                    float outv = hnv[t][i] + o2[t][i] + b2;
                    float xn = xf[t][i] + dt * outv;
                    xf[t][i] = xn;
                    xS[(tB*16 + q*4 + i)*136 + cg*32 + t*16 + r] = f2bf(xn);
                }
            }
            __syncthreads();   // xS (and cuS reuse) ready for next step
        } else {
#pragma unroll
            for (int t = 0; t < 2; ++t) {
                float b2 = f2_b[cg*32 + t*16 + r];
#pragma unroll
                for (int i = 0; i < 4; ++i) {
                    float outv = hnv[t][i] + o2[t][i] + b2;
                    outp[(size_t)(row0 + tB*16 + q*4 + i)*AA + cg*32 + t*16 + r] = xf[t][i] + dt * outv;
                }
            }
        }
    }
}

extern "C" void kernel_launch(void* const* d_in, const int* in_sizes, int n_in,
                              void* d_out, int out_size, void* d_ws, size_t ws_size,
                              hipStream_t stream) {
    const float* cond   = (const float*)d_in[0];
    const float* noise  = (const float*)d_in[1];
    const float* t1_w   = (const float*)d_in[2];
    const float* t1_b   = (const float*)d_in[3];
    const float* t2_w   = (const float*)d_in[4];
    const float* t2_b   = (const float*)d_in[5];
    const float* qp_w   = (const float*)d_in[6];
    const float* qp_b   = (const float*)d_in[7];
    const float* in_w   = (const float*)d_in[8];
    const float* in_b   = (const float*)d_in[9];
    const float* op_w   = (const float*)d_in[10];
    const float* op_b   = (const float*)d_in[11];
    const float* outp_w = (const float*)d_in[12];
    const float* outp_b = (const float*)d_in[13];
    const float* f1_w   = (const float*)d_in[14];
    const float* f1_b   = (const float*)d_in[15];
    const float* f2_w   = (const float*)d_in[16];
    const float* f2_b   = (const float*)d_in[17];
    const float* ln_g   = (const float*)d_in[18];
    const float* ln_bp  = (const float*)d_in[19];

    char* w = (char*)d_ws;
    auto alloc = [&](size_t bytes) {
        char* p = w;
        w += (bytes + 255) & ~(size_t)255;
        return p;
    };
    unsigned char*  K8     = (unsigned char*)alloc((size_t)NB*HH*CL*HD);      // 16.8 MB fp8
    unsigned char*  V8     = (unsigned char*)alloc((size_t)NB*HH*HD*CL);      // 16.8 MB fp8
    unsigned short* condb  = (unsigned short*)alloc((size_t)NB*CL*EE*2);      // 33.5 MB
    unsigned short* wkv_bf = (unsigned short*)alloc((size_t)1024*512*2);      // 1 MB
    unsigned short* wq_bf  = (unsigned short*)alloc((size_t)512*128*2);
    unsigned short* wo_bf  = (unsigned short*)alloc((size_t)128*512*2);
    unsigned short* f1_bf  = (unsigned short*)alloc((size_t)512*128*2);
    unsigned short* f2_bf  = (unsigned short*)alloc((size_t)128*512*2);
    float*          bo_eff = (float*)alloc(128*4);
    float*          tembB  = (float*)alloc((size_t)NSTEPS*512*4);
    float*          qbiasB = (float*)alloc((size_t)NSTEPS*512*4);
    (void)ws_size; (void)n_in; (void)in_sizes; (void)out_size;

    // --- one-time prep ---
    cvt8_kernel<<<8192, 256, 0, stream>>>(cond, condb, NB*CL*EE/8);
    cvt8_kernel<<<256, 256, 0, stream>>>(in_w + 512*512, wkv_bf, 1024*512/8);
    cvt8_kernel<<<32, 256, 0, stream>>>(f1_w, f1_bf, 512*128/8);
    cvt8_kernel<<<32, 256, 0, stream>>>(f2_w, f2_bf, 128*512/8);
    prep_eff_kernel<<<513, 256, 0, stream>>>(in_w, qp_w, outp_w, op_w, op_b, outp_b,
                                             wq_bf, wo_bf, bo_eff);
    temb_kernel<<<40, 256, 0, stream>>>(t1_w, t1_b, t2_w, t2_b, tembB);
    qbias_kernel<<<40, 256, 0, stream>>>(in_w, in_b, qp_b, tembB, qbiasB);
    kv_kernel<<<2048, 512, 0, stream>>>(condb, wkv_bf, in_b + 512, K8, V8);

    // --- all 20 denoise steps, one kernel, 256 blocks x 8 waves ---
    mega_kernel<<<256, 512, 0, stream>>>(K8, V8, noise, wq_bf, qbiasB,
                                         wo_bf, bo_eff, ln_g, ln_bp,
                                         f1_bf, f1_b, f2_bf, f2_b,
                                         (float*)d_out);
}